// Round 5
// baseline (860.917 us; speedup 1.0000x reference)
//
#include <hip/hip_runtime.h>
#include <stdint.h>

__device__ inline float bf2f(unsigned short b) {
    unsigned u = ((unsigned)b) << 16;
    return __builtin_bit_cast(float, u);
}
__device__ inline unsigned short f2bf(float f) {
    unsigned u = __builtin_bit_cast(unsigned, f);
    unsigned r = (u + 0x7fffu + ((u >> 16) & 1u)) >> 16;
    return (unsigned short)r;
}
// order-preserving float<->uint for atomicMax over floats (incl. negatives)
__device__ inline unsigned encf(float f) {
    unsigned u = __builtin_bit_cast(unsigned, f);
    return (u >> 31) ? ~u : (u | 0x80000000u);
}
__device__ inline float decf(unsigned k) {
    unsigned u = (k >> 31) ? (k & 0x7fffffffu) : ~k;
    return __builtin_bit_cast(float, u);
}
__device__ inline float ldf(const void* p, int i, int f32) {
    return f32 ? ((const float*)p)[i] : bf2f(((const unsigned short*)p)[i]);
}
__device__ inline int lde(const int* ei, int idx, int is64) {
    return is64 ? ei[2 * idx] : ei[idx];
}

// ---- K_det: input dtype layouts, decided on-device every launch ----
// flags[0]=float inputs fp32 (else bf16); flags[1]=edge_index int64-layout
__global__ void k_det(const void* x, const int* ei, int* flags) {
    __shared__ int h1, h2;
    if (threadIdx.x == 0) { h1 = 0; h2 = 0; }
    __syncthreads();
    const unsigned short* xs = (const unsigned short*)x;
    int c1 = 0;
    for (int i = threadIdx.x * 2; i < 65536; i += 512)
        if ((xs[i] & 0x7f80u) == 0x7f80u) c1++;   // fp32 mantissa halves hit this ~1/256
    int c2 = 0;
    for (int i = threadIdx.x * 2 + 1; i < 8192; i += 512)
        if (ei[i] != 0) c2++;                      // int64 high words are all 0
    atomicAdd(&h1, c1);
    atomicAdd(&h2, c2);
    __syncthreads();
    if (threadIdx.x == 0) { flags[0] = (h1 >= 8); flags[1] = (h2 < 8); }
}

// ---- generic zero ----
__global__ void k_zero(float* p, int n) {
    int i = blockIdx.x * blockDim.x + threadIdx.x;
    int s = gridDim.x * blockDim.x;
    for (int j = i; j < n; j += s) p[j] = 0.f;
}
__global__ void k_zero_u(unsigned* p) { if (threadIdx.x == 0 && blockIdx.x == 0) *p = 0u; }

// ---- K1: proj = x@W (pure VALU) + fused per-node scores ----
__global__ __launch_bounds__(256) void k1_proj(
    const void* __restrict__ x, const void* __restrict__ W,
    const void* __restrict__ a_src, const void* __restrict__ a_trg,
    const int* __restrict__ flags, unsigned short* __restrict__ projb,
    float* __restrict__ ssrc, float* __restrict__ strg, int N)
{
    __shared__ float xs[8][128];
    int f32 = flags[0];
    int t = threadIdx.x;
    int n0 = blockIdx.x * 8;
    for (int idx = t; idx < 8 * 128; idx += 256) {
        int row = idx >> 7, col = idx & 127;
        int n = n0 + row;
        if (n >= N) n = N - 1;
        xs[row][col] = ldf(x, n * 128 + col, f32);
    }
    __syncthreads();
    int j = t & 127, rg = t >> 7;
    float acc[4] = {0.f, 0.f, 0.f, 0.f};
    for (int k = 0; k < 128; k++) {
        float w = ldf(W, k * 128 + j, f32);
#pragma unroll
        for (int rr = 0; rr < 4; rr++)
            acc[rr] = fmaf(xs[rg * 4 + rr][k], w, acc[rr]);
    }
#pragma unroll
    for (int rr = 0; rr < 4; rr++) {
        int n = n0 + rg * 4 + rr;
        if (n < N) projb[(size_t)n * 128 + j] = f2bf(acc[rr]);
    }
    float av = ldf(a_src, j, f32);
    float bv = ldf(a_trg, j, f32);
    float ps[4], pt[4];
#pragma unroll
    for (int rr = 0; rr < 4; rr++) { ps[rr] = acc[rr] * av; pt[rr] = acc[rr] * bv; }
#pragma unroll
    for (int k = 1; k < 32; k <<= 1) {
#pragma unroll
        for (int rr = 0; rr < 4; rr++) {
            ps[rr] += __shfl_xor(ps[rr], k, 32);
            pt[rr] += __shfl_xor(pt[rr], k, 32);
        }
    }
    if ((t & 31) == 0) {
        int h = (t >> 5) & 3;
#pragma unroll
        for (int rr = 0; rr < 4; rr++) {
            int n = n0 + rg * 4 + rr;
            if (n < N) {
                ssrc[n * 4 + h] = ps[rr];
                strg[n * 4 + h] = pt[rr];
            }
        }
    }
}

__device__ inline void edge_scores(const float* ssrc, const float* strg,
                                   int src, int trg, float* v) {
    float4 a = *(const float4*)(ssrc + (size_t)src * 4);
    float4 b = *(const float4*)(strg + (size_t)trg * 4);
    v[0] = a.x + b.x; v[1] = a.y + b.y; v[2] = a.z + b.z; v[3] = a.w + b.w;
#pragma unroll
    for (int h = 0; h < 4; h++) v[h] = v[h] > 0.f ? v[h] : 0.2f * v[h];
}

// ---- KM: global max of leaky edge scores ----
__global__ __launch_bounds__(256) void kM_max(
    const int* __restrict__ ei, const float* __restrict__ ssrc,
    const float* __restrict__ strg, const int* __restrict__ flags,
    unsigned* __restrict__ Menc, int E, int N)
{
    int e64 = flags[1];
    int e = blockIdx.x * 256 + threadIdx.x;
    float m = -3.0e38f;
    if (e < E) {
        int src = min(max(lde(ei, e, e64), 0), N - 1);
        int trg = min(max(lde(ei, E + e, e64), 0), N - 1);
        float v[4];
        edge_scores(ssrc, strg, src, trg, v);
        m = fmaxf(fmaxf(v[0], v[1]), fmaxf(v[2], v[3]));
    }
#pragma unroll
    for (int k = 1; k < 64; k <<= 1) m = fmaxf(m, __shfl_xor(m, k, 64));
    if ((threadIdx.x & 63) == 0) atomicMax(Menc, encf(m));
}

// ---- KD: denominators, edge-parallel atomics (segment_sum clone) ----
__global__ __launch_bounds__(256) void kD_den(
    const int* __restrict__ ei, const float* __restrict__ ssrc,
    const float* __restrict__ strg, const int* __restrict__ flags,
    const unsigned* __restrict__ Menc, float* __restrict__ den, int E, int N)
{
    int e64 = flags[1];
    int e = blockIdx.x * 256 + threadIdx.x;
    if (e >= E) return;
    float M = decf(*Menc);
    int src = min(max(lde(ei, e, e64), 0), N - 1);
    int trg = min(max(lde(ei, E + e, e64), 0), N - 1);
    float v[4];
    edge_scores(ssrc, strg, src, trg, v);
#pragma unroll
    for (int h = 0; h < 4; h++) atomicAdd(&den[trg * 4 + h], __expf(v[h] - M));
}

// ---- KAgg: edge-parallel weighted scatter of a 64-feature chunk ----
__global__ __launch_bounds__(256) void kAgg(
    const int* __restrict__ ei, const float* __restrict__ ssrc,
    const float* __restrict__ strg, const float* __restrict__ den,
    const unsigned short* __restrict__ projb, const int* __restrict__ flags,
    const unsigned* __restrict__ Menc, float* __restrict__ outf,
    int j0, int E, int N)
{
    int e64 = flags[1];
    int lane = threadIdx.x & 63;
    int gw = blockIdx.x * 4 + (threadIdx.x >> 6);
    int nw = gridDim.x * 4;
    float M = decf(*Menc);
    int j = j0 + lane;
    int hsel = j >> 5;
    for (int e = gw; e < E; e += nw) {
        int src = min(max(lde(ei, e, e64), 0), N - 1);
        int trg = min(max(lde(ei, E + e, e64), 0), N - 1);
        float v[4];
        edge_scores(ssrc, strg, src, trg, v);
        float4 dn = *(const float4*)(den + (size_t)trg * 4);
        float dd[4] = {dn.x, dn.y, dn.z, dn.w};
        float att = __expf(v[hsel] - M) / (dd[hsel] + 1e-16f);
        float p = bf2f(projb[(size_t)src * 128 + j]);
        atomicAdd(&outf[(size_t)trg * 64 + lane], p * att);
    }
}

// ---- KFin: out[:, j0:j0+64] = elu(outf + x + bias), FP32 store ----
__global__ __launch_bounds__(256) void kFin(
    const float* __restrict__ outf, const void* __restrict__ x,
    const void* __restrict__ bias, const int* __restrict__ flags,
    float* __restrict__ out, int j0, int N)
{
    int f32 = flags[0];
    int idx = blockIdx.x * 256 + threadIdx.x;
    if (idx >= N * 64) return;
    int n = idx >> 6, l = idx & 63;
    int j = j0 + l;
    float o = outf[idx] + ldf(x, n * 128 + j, f32) + ldf(bias, j, f32);
    o = o > 0.f ? o : __expf(o) - 1.f;
    out[(size_t)n * 128 + j] = o;
}

// ================= CSR fallback (small workspace only) =================
__global__ void k0_init(int* counts, int* cursor, unsigned* Menc, int N) {
    int i = blockIdx.x * blockDim.x + threadIdx.x;
    if (i <= N) counts[i] = 0;
    if (i < N) cursor[i] = 0;
    if (i == 0) *Menc = 0u;
}
__global__ __launch_bounds__(256) void k2a_count(
    const int* __restrict__ ei, const int* __restrict__ flags,
    int* __restrict__ counts, int E, int N)
{
    int e64 = flags[1];
    int e = blockIdx.x * 256 + threadIdx.x;
    if (e >= E) return;
    int trg = min(max(lde(ei, E + e, e64), 0), N - 1);
    atomicAdd(&counts[trg], 1);
}
__global__ __launch_bounds__(1024) void k2b_scan(
    const int* __restrict__ counts, int* __restrict__ offsets, int NP1)
{
    __shared__ int lds[1024];
    int t = threadIdx.x;
    int C = (NP1 + 1023) >> 10;
    int lo = t * C, hi = min(lo + C, NP1);
    int s = 0;
    for (int i = lo; i < hi; i++) s += counts[i];
    lds[t] = s;
    __syncthreads();
    int incl = s;
    for (int st = 1; st < 1024; st <<= 1) {
        int add = (t >= st) ? lds[t - st] : 0;
        __syncthreads();
        incl += add;
        lds[t] = incl;
        __syncthreads();
    }
    int run = incl - s;
    for (int i = lo; i < hi; i++) { offsets[i] = run; run += counts[i]; }
}
__global__ __launch_bounds__(256) void k2c_scatter(
    const int* __restrict__ ei, const int* __restrict__ offsets,
    const int* __restrict__ flags, int* __restrict__ cursor,
    int* __restrict__ esrc, int E, int N)
{
    int e64 = flags[1];
    int e = blockIdx.x * 256 + threadIdx.x;
    if (e >= E) return;
    int src = min(max(lde(ei, e, e64), 0), N - 1);
    int trg = min(max(lde(ei, E + e, e64), 0), N - 1);
    int pos = offsets[trg] + atomicAdd(&cursor[trg], 1);
    if (pos >= 0 && pos < E) esrc[pos] = src;
}
__global__ __launch_bounds__(64) void k3_agg(
    const int* __restrict__ offsets, const int* __restrict__ esrc,
    const float* __restrict__ ssrc, const float* __restrict__ strg,
    const unsigned short* __restrict__ projb, const void* __restrict__ x,
    const void* __restrict__ bias, const int* __restrict__ flags,
    const unsigned* __restrict__ Menc, float* __restrict__ out, int N, int E)
{
    int n = blockIdx.x;
    int lane = threadIdx.x;
    int f32 = flags[0];
    int off = offsets[n], end = offsets[n + 1];
    int d = end - off;
    d = max(0, min(d, E));
    float M = decf(*Menc);
    float4 stv = *(const float4*)(strg + (size_t)n * 4);
    float st[4] = {stv.x, stv.y, stv.z, stv.w};
    float den[4] = {0.f, 0.f, 0.f, 0.f};
    for (int i = lane; i < d; i += 64) {
        int s = min(max(esrc[off + i], 0), N - 1);
        float4 ssv = *(const float4*)(ssrc + (size_t)s * 4);
        float sv[4] = {ssv.x, ssv.y, ssv.z, ssv.w};
#pragma unroll
        for (int h = 0; h < 4; h++) {
            float v = sv[h] + st[h];
            v = v > 0.f ? v : 0.2f * v;
            den[h] += __expf(v - M);
        }
    }
#pragma unroll
    for (int k = 1; k < 64; k <<= 1)
#pragma unroll
        for (int h = 0; h < 4; h++) den[h] += __shfl_xor(den[h], k, 64);
    float inv[4];
#pragma unroll
    for (int h = 0; h < 4; h++) inv[h] = 1.0f / (den[h] + 1e-16f);
    __shared__ int lsrc[256];
    __shared__ float latt[256 * 5];
    float acc0 = 0.f, acc1 = 0.f;
    int h01 = lane >> 4;
    for (int base = 0; base < d; base += 256) {
        int cd = min(256, d - base);
        for (int i = lane; i < cd; i += 64) {
            int s = min(max(esrc[off + base + i], 0), N - 1);
            lsrc[i] = s;
            float4 ssv = *(const float4*)(ssrc + (size_t)s * 4);
            float sv[4] = {ssv.x, ssv.y, ssv.z, ssv.w};
#pragma unroll
            for (int h = 0; h < 4; h++) {
                float v = sv[h] + st[h];
                v = v > 0.f ? v : 0.2f * v;
                latt[i * 5 + h] = __expf(v - M) * inv[h];
            }
        }
        __syncthreads();
        for (int k = 0; k < cd; k++) {
            int s = lsrc[k];
            float att = latt[k * 5 + h01];
            unsigned p = *(const unsigned*)(projb + (size_t)s * 128 + lane * 2);
            acc0 = fmaf(bf2f((unsigned short)(p & 0xffffu)), att, acc0);
            acc1 = fmaf(bf2f((unsigned short)(p >> 16)), att, acc1);
        }
        __syncthreads();
    }
    int j0 = lane * 2;
    float o0 = acc0 + ldf(x, n * 128 + j0, f32) + ldf(bias, j0, f32);
    float o1 = acc1 + ldf(x, n * 128 + j0 + 1, f32) + ldf(bias, j0 + 1, f32);
    o0 = o0 > 0.f ? o0 : __expf(o0) - 1.f;
    o1 = o1 > 0.f ? o1 : __expf(o1) - 1.f;
    out[(size_t)n * 128 + j0]     = o0;
    out[(size_t)n * 128 + j0 + 1] = o1;
}

extern "C" void kernel_launch(void* const* d_in, const int* in_sizes, int n_in,
                              void* d_out, int out_size, void* d_ws, size_t ws_size,
                              hipStream_t stream)
{
    const void* x     = d_in[0];
    const int*  ei    = (const int*)d_in[1];
    const void* W     = d_in[2];
    const void* a_src = d_in[3];
    const void* a_trg = d_in[4];
    const void* bias  = d_in[5];
    float* out = (float*)d_out;   // reference output dtype is float32
    int N = in_sizes[0] / 128;
    int E = N * 16;
    if (in_sizes[1] / 2 < E) E = in_sizes[1] / 2;

    char* ws = (char*)d_ws;
    size_t o = 0;
    auto alloc = [&](size_t bytes) {
        size_t r = o;
        o = (o + bytes + 255) & ~(size_t)255;
        return r;
    };
    int* flags = (int*)(ws + alloc(256));
    unsigned short* projb = (unsigned short*)(ws + alloc((size_t)N * 128 * 2));
    float* ssrc = (float*)(ws + alloc((size_t)N * 4 * 4));
    float* strg = (float*)(ws + alloc((size_t)N * 4 * 4));
    unsigned* Menc = (unsigned*)(ws + alloc(256));
    size_t base = o;

    k_det<<<1, 256, 0, stream>>>(x, ei, flags);
    k_zero_u<<<1, 64, 0, stream>>>(Menc);
    k1_proj<<<(N + 7) / 8, 256, 0, stream>>>(x, W, a_src, a_trg, flags, projb, ssrc, strg, N);
    kM_max<<<(E + 255) / 256, 256, 0, stream>>>(ei, ssrc, strg, flags, Menc, E, N);

    size_t need_atomic = base + ((size_t)N * 4 * 4 + 256) + ((size_t)N * 64 * 4 + 256);
    if (ws_size >= need_atomic) {
        float* den  = (float*)(ws + alloc((size_t)N * 4 * 4));
        float* outf = (float*)(ws + alloc((size_t)N * 64 * 4));
        k_zero<<<512, 256, 0, stream>>>(den, N * 4);
        kD_den<<<(E + 255) / 256, 256, 0, stream>>>(ei, ssrc, strg, flags, Menc, den, E, N);
        for (int j0 = 0; j0 < 128; j0 += 64) {
            k_zero<<<2048, 256, 0, stream>>>(outf, N * 64);
            kAgg<<<8192, 256, 0, stream>>>(ei, ssrc, strg, den, projb, flags, Menc,
                                           outf, j0, E, N);
            kFin<<<(N * 64 + 255) / 256, 256, 0, stream>>>(outf, x, bias, flags, out, j0, N);
        }
    } else {
        int* counts  = (int*)(ws + alloc((size_t)(N + 1) * 4));
        int* offsets = (int*)(ws + alloc((size_t)(N + 1) * 4));
        int* cursor  = (int*)(ws + alloc((size_t)N * 4));
        int* esrc    = (int*)(ws + alloc((size_t)E * 4));
        k0_init<<<(N + 256) / 256, 256, 0, stream>>>(counts, cursor, Menc, N);
        kM_max<<<(E + 255) / 256, 256, 0, stream>>>(ei, ssrc, strg, flags, Menc, E, N);
        k2a_count<<<(E + 255) / 256, 256, 0, stream>>>(ei, flags, counts, E, N);
        k2b_scan<<<1, 1024, 0, stream>>>(counts, offsets, N + 1);
        k2c_scatter<<<(E + 255) / 256, 256, 0, stream>>>(ei, offsets, flags, cursor, esrc, E, N);
        k3_agg<<<N, 64, 0, stream>>>(offsets, esrc, ssrc, strg, projb, x, bias, flags,
                                     Menc, out, N, E);
    }
}

// Round 6
// 495.292 us; speedup vs baseline: 1.7382x; 1.7382x over previous
//
#include <hip/hip_runtime.h>
#include <stdint.h>

__device__ inline float bf2f(unsigned short b) {
    unsigned u = ((unsigned)b) << 16;
    return __builtin_bit_cast(float, u);
}
__device__ inline unsigned short f2bf(float f) {
    unsigned u = __builtin_bit_cast(unsigned, f);
    unsigned r = (u + 0x7fffu + ((u >> 16) & 1u)) >> 16;
    return (unsigned short)r;
}
// order-preserving float<->uint for atomicMax over floats (incl. negatives)
__device__ inline unsigned encf(float f) {
    unsigned u = __builtin_bit_cast(unsigned, f);
    return (u >> 31) ? ~u : (u | 0x80000000u);
}
__device__ inline float decf(unsigned k) {
    unsigned u = (k >> 31) ? (k & 0x7fffffffu) : ~k;
    return __builtin_bit_cast(float, u);
}
__device__ inline float ldf(const void* p, int i, int f32) {
    return f32 ? ((const float*)p)[i] : bf2f(((const unsigned short*)p)[i]);
}
__device__ inline int lde(const int* ei, int idx, int is64) {
    return is64 ? ei[2 * idx] : ei[idx];
}

// ---- K_det: input dtype layouts (deterministic, every launch) ----
__global__ void k_det(const void* x, const int* ei, int* flags) {
    __shared__ int h1, h2;
    if (threadIdx.x == 0) { h1 = 0; h2 = 0; }
    __syncthreads();
    const unsigned short* xs = (const unsigned short*)x;
    int c1 = 0;
    for (int i = threadIdx.x * 2; i < 65536; i += 512)
        if ((xs[i] & 0x7f80u) == 0x7f80u) c1++;   // fp32 mantissa halves ~1/256; bf16 never
    int c2 = 0;
    for (int i = threadIdx.x * 2 + 1; i < 8192; i += 512)
        if (ei[i] != 0) c2++;                      // int64 high words are 0
    atomicAdd(&h1, c1);
    atomicAdd(&h2, c2);
    __syncthreads();
    if (threadIdx.x == 0) { flags[0] = (h1 >= 8); flags[1] = (h2 < 8); }
}

// ---- K0: zero counts/cursor, init Menc ----
__global__ void k0_init(int* counts, int* cursor, unsigned* Menc, int N) {
    int i = blockIdx.x * blockDim.x + threadIdx.x;
    if (i <= N) counts[i] = 0;
    if (i < N) cursor[i] = 0;
    if (i == 0) *Menc = 0u;
}

// ---- K1: proj = x@W (VALU, 16 rows/block) + fused per-node scores ----
__global__ __launch_bounds__(256) void k1_proj(
    const void* __restrict__ x, const void* __restrict__ W,
    const void* __restrict__ a_src, const void* __restrict__ a_trg,
    const int* __restrict__ flags, unsigned short* __restrict__ projb,
    float* __restrict__ ssrc, float* __restrict__ strg, int N)
{
    __shared__ float xs[16][128];
    int f32 = flags[0];
    int t = threadIdx.x;
    int n0 = blockIdx.x * 16;
    for (int idx = t; idx < 16 * 128; idx += 256) {
        int row = idx >> 7, col = idx & 127;
        int n = n0 + row;
        if (n >= N) n = N - 1;
        xs[row][col] = ldf(x, n * 128 + col, f32);
    }
    __syncthreads();
    int j = t & 127, rg = t >> 7;   // rg in {0,1}: rows rg*8 .. rg*8+7
    float acc[8] = {0.f, 0.f, 0.f, 0.f, 0.f, 0.f, 0.f, 0.f};
    for (int k = 0; k < 128; k++) {
        float w = ldf(W, k * 128 + j, f32);
#pragma unroll
        for (int rr = 0; rr < 8; rr++)
            acc[rr] = fmaf(xs[rg * 8 + rr][k], w, acc[rr]);  // broadcast LDS read
    }
#pragma unroll
    for (int rr = 0; rr < 8; rr++) {
        int n = n0 + rg * 8 + rr;
        if (n < N) projb[(size_t)n * 128 + j] = f2bf(acc[rr]);
    }
    float av = ldf(a_src, j, f32);
    float bv = ldf(a_trg, j, f32);
    float ps[8], pt[8];
#pragma unroll
    for (int rr = 0; rr < 8; rr++) { ps[rr] = acc[rr] * av; pt[rr] = acc[rr] * bv; }
#pragma unroll
    for (int k = 1; k < 32; k <<= 1) {
#pragma unroll
        for (int rr = 0; rr < 8; rr++) {
            ps[rr] += __shfl_xor(ps[rr], k, 32);
            pt[rr] += __shfl_xor(pt[rr], k, 32);
        }
    }
    if ((t & 31) == 0) {
        int h = (t >> 5) & 3;   // == j>>5
#pragma unroll
        for (int rr = 0; rr < 8; rr++) {
            int n = n0 + rg * 8 + rr;
            if (n < N) {
                ssrc[n * 4 + h] = ps[rr];
                strg[n * 4 + h] = pt[rr];
            }
        }
    }
}

__device__ inline void edge_scores(const float* ssrc, const float* strg,
                                   int src, int trg, float* v) {
    float4 a = *(const float4*)(ssrc + (size_t)src * 4);
    float4 b = *(const float4*)(strg + (size_t)trg * 4);
    v[0] = a.x + b.x; v[1] = a.y + b.y; v[2] = a.z + b.z; v[3] = a.w + b.w;
#pragma unroll
    for (int h = 0; h < 4; h++) v[h] = v[h] > 0.f ? v[h] : 0.2f * v[h];
}

// ---- KE: fused in-degree histogram + global max (one edge pass) ----
__global__ __launch_bounds__(256) void kE_count_max(
    const int* __restrict__ ei, const float* __restrict__ ssrc,
    const float* __restrict__ strg, const int* __restrict__ flags,
    int* __restrict__ counts, unsigned* __restrict__ Menc, int E, int N)
{
    int e64 = flags[1];
    int e = blockIdx.x * 256 + threadIdx.x;
    float m = -3.0e38f;
    if (e < E) {
        int src = min(max(lde(ei, e, e64), 0), N - 1);
        int trg = min(max(lde(ei, E + e, e64), 0), N - 1);
        atomicAdd(&counts[trg], 1);
        float v[4];
        edge_scores(ssrc, strg, src, trg, v);
        m = fmaxf(fmaxf(v[0], v[1]), fmaxf(v[2], v[3]));
    }
#pragma unroll
    for (int k = 1; k < 64; k <<= 1) m = fmaxf(m, __shfl_xor(m, k, 64));
    if ((threadIdx.x & 63) == 0) atomicMax(Menc, encf(m));
}

// ---- K2b: exclusive scan counts -> offsets (single block) ----
__global__ __launch_bounds__(1024) void k2b_scan(
    const int* __restrict__ counts, int* __restrict__ offsets, int NP1)
{
    __shared__ int lds[1024];
    int t = threadIdx.x;
    int C = (NP1 + 1023) >> 10;
    int lo = t * C, hi = min(lo + C, NP1);
    int s = 0;
    for (int i = lo; i < hi; i++) s += counts[i];
    lds[t] = s;
    __syncthreads();
    int incl = s;
    for (int st = 1; st < 1024; st <<= 1) {
        int add = (t >= st) ? lds[t - st] : 0;
        __syncthreads();
        incl += add;
        lds[t] = incl;
        __syncthreads();
    }
    int run = incl - s;
    for (int i = lo; i < hi; i++) { offsets[i] = run; run += counts[i]; }
}

// ---- K2c: scatter edges into CSR buckets ----
__global__ __launch_bounds__(256) void k2c_scatter(
    const int* __restrict__ ei, const int* __restrict__ offsets,
    const int* __restrict__ flags, int* __restrict__ cursor,
    int* __restrict__ esrc, int E, int N)
{
    int e64 = flags[1];
    int e = blockIdx.x * 256 + threadIdx.x;
    if (e >= E) return;
    int src = min(max(lde(ei, e, e64), 0), N - 1);
    int trg = min(max(lde(ei, E + e, e64), 0), N - 1);
    int pos = offsets[trg] + atomicAdd(&cursor[trg], 1);
    if (pos >= 0 && pos < E) esrc[pos] = src;
}

// ---- K3: per-node softmax + gather-aggregate + skip + bias + ELU (4 nodes/block) ----
__global__ __launch_bounds__(256) void k3_agg(
    const int* __restrict__ offsets, const int* __restrict__ esrc,
    const float* __restrict__ ssrc, const float* __restrict__ strg,
    const unsigned short* __restrict__ projb, const void* __restrict__ x,
    const void* __restrict__ bias, const int* __restrict__ flags,
    const unsigned* __restrict__ Menc, float* __restrict__ out, int N, int E)
{
    int w = threadIdx.x >> 6;      // wave 0..3, one node per wave
    int lane = threadIdx.x & 63;
    int n = blockIdx.x * 4 + w;
    int f32 = flags[0];
    bool valid = (n < N);
    int nc = valid ? n : N - 1;

    int off = offsets[nc];
    int d = offsets[nc + 1] - off;
    d = max(0, min(d, E));
    if (!valid) d = 0;

    float M = decf(*Menc);
    float4 stv = *(const float4*)(strg + (size_t)nc * 4);
    float st[4] = {stv.x, stv.y, stv.z, stv.w};

    // Pass A: denominators (lanes stride edges; shuffle-reduce)
    float den[4] = {0.f, 0.f, 0.f, 0.f};
    for (int i = lane; i < d; i += 64) {
        int s = min(max(esrc[off + i], 0), N - 1);
        float4 ssv = *(const float4*)(ssrc + (size_t)s * 4);
        float sv[4] = {ssv.x, ssv.y, ssv.z, ssv.w};
#pragma unroll
        for (int h = 0; h < 4; h++) {
            float v = sv[h] + st[h];
            v = v > 0.f ? v : 0.2f * v;
            den[h] += __expf(v - M);
        }
    }
#pragma unroll
    for (int k = 1; k < 64; k <<= 1)
#pragma unroll
        for (int h = 0; h < 4; h++) den[h] += __shfl_xor(den[h], k, 64);
    float inv[4];
#pragma unroll
    for (int h = 0; h < 4; h++) inv[h] = 1.0f / (den[h] + 1e-16f);

    // block-uniform chunk count so __syncthreads is non-divergent
    __shared__ int dmax_s[4];
    if (lane == 0) dmax_s[w] = d;
    __syncthreads();
    int dmx = max(max(dmax_s[0], dmax_s[1]), max(dmax_s[2], dmax_s[3]));

    __shared__ int lsrc[4][64];
    __shared__ float latt[4][64 * 5];   // stride 5: conflict-free fill
    float acc0 = 0.f, acc1 = 0.f;
    int h01 = lane >> 4;                // head of features 2*lane, 2*lane+1
    for (int base = 0; base < dmx; base += 64) {
        int cd = min(64, d - base);     // may be <=0 for this wave
        if (lane < cd) {
            int s = min(max(esrc[off + base + lane], 0), N - 1);
            lsrc[w][lane] = s;
            float4 ssv = *(const float4*)(ssrc + (size_t)s * 4);
            float sv[4] = {ssv.x, ssv.y, ssv.z, ssv.w};
#pragma unroll
            for (int h = 0; h < 4; h++) {
                float v = sv[h] + st[h];
                v = v > 0.f ? v : 0.2f * v;
                latt[w][lane * 5 + h] = __expf(v - M) * inv[h];
            }
        }
        __syncthreads();
        for (int k = 0; k < cd; k++) {
            int s = lsrc[w][k];
            float att = latt[w][k * 5 + h01];
            unsigned p = *(const unsigned*)(projb + (size_t)s * 128 + lane * 2);
            acc0 = fmaf(bf2f((unsigned short)(p & 0xffffu)), att, acc0);
            acc1 = fmaf(bf2f((unsigned short)(p >> 16)), att, acc1);
        }
        __syncthreads();
    }

    if (!valid) return;
    int j0 = lane * 2;
    float o0 = acc0 + ldf(x, n * 128 + j0, f32) + ldf(bias, j0, f32);
    float o1 = acc1 + ldf(x, n * 128 + j0 + 1, f32) + ldf(bias, j0 + 1, f32);
    o0 = o0 > 0.f ? o0 : __expf(o0) - 1.f;
    o1 = o1 > 0.f ? o1 : __expf(o1) - 1.f;
    out[(size_t)n * 128 + j0]     = o0;
    out[(size_t)n * 128 + j0 + 1] = o1;
}

extern "C" void kernel_launch(void* const* d_in, const int* in_sizes, int n_in,
                              void* d_out, int out_size, void* d_ws, size_t ws_size,
                              hipStream_t stream)
{
    const void* x     = d_in[0];
    const int*  ei    = (const int*)d_in[1];
    const void* W     = d_in[2];
    const void* a_src = d_in[3];
    const void* a_trg = d_in[4];
    const void* bias  = d_in[5];
    float* out = (float*)d_out;   // reference output dtype is float32
    int N = in_sizes[0] / 128;
    int E = N * 16;
    if (in_sizes[1] / 2 < E) E = in_sizes[1] / 2;

    char* ws = (char*)d_ws;
    size_t o = 0;
    auto alloc = [&](size_t bytes) {
        size_t r = o;
        o = (o + bytes + 255) & ~(size_t)255;
        return r;
    };
    int* flags = (int*)(ws + alloc(256));
    unsigned short* projb = (unsigned short*)(ws + alloc((size_t)N * 128 * 2));
    float* ssrc  = (float*)(ws + alloc((size_t)N * 4 * 4));
    float* strg  = (float*)(ws + alloc((size_t)N * 4 * 4));
    unsigned* Menc = (unsigned*)(ws + alloc(256));
    int* counts  = (int*)(ws + alloc((size_t)(N + 1) * 4));
    int* offsets = (int*)(ws + alloc((size_t)(N + 1) * 4));
    int* cursor  = (int*)(ws + alloc((size_t)N * 4));
    int* esrc    = (int*)(ws + alloc((size_t)E * 4));

    k_det<<<1, 256, 0, stream>>>(x, ei, flags);
    k0_init<<<(N + 256) / 256, 256, 0, stream>>>(counts, cursor, Menc, N);
    k1_proj<<<(N + 15) / 16, 256, 0, stream>>>(x, W, a_src, a_trg, flags, projb, ssrc, strg, N);
    kE_count_max<<<(E + 255) / 256, 256, 0, stream>>>(ei, ssrc, strg, flags, counts, Menc, E, N);
    k2b_scan<<<1, 1024, 0, stream>>>(counts, offsets, N + 1);
    k2c_scatter<<<(E + 255) / 256, 256, 0, stream>>>(ei, offsets, flags, cursor, esrc, E, N);
    k3_agg<<<(N + 3) / 4, 256, 0, stream>>>(offsets, esrc, ssrc, strg, projb, x, bias, flags,
                                            Menc, out, N, E);
}

// Round 7
// 377.196 us; speedup vs baseline: 2.2824x; 1.3131x over previous
//
#include <hip/hip_runtime.h>
#include <stdint.h>

__device__ inline float bf2f(unsigned short b) {
    unsigned u = ((unsigned)b) << 16;
    return __builtin_bit_cast(float, u);
}
__device__ inline unsigned short f2bf(float f) {
    unsigned u = __builtin_bit_cast(unsigned, f);
    unsigned r = (u + 0x7fffu + ((u >> 16) & 1u)) >> 16;
    return (unsigned short)r;
}
__device__ inline float ldf(const void* p, int i, int f32) {
    return f32 ? ((const float*)p)[i] : bf2f(((const unsigned short*)p)[i]);
}
__device__ inline int lde(const int* ei, int idx, int is64) {
    return is64 ? ei[2 * idx] : ei[idx];
}

// ---- K_det: input dtype layouts (deterministic, every launch) ----
__global__ void k_det(const void* x, const int* ei, int* flags) {
    __shared__ int h1, h2;
    if (threadIdx.x == 0) { h1 = 0; h2 = 0; }
    __syncthreads();
    const unsigned short* xs = (const unsigned short*)x;
    int c1 = 0;
    for (int i = threadIdx.x * 2; i < 65536; i += 512)
        if ((xs[i] & 0x7f80u) == 0x7f80u) c1++;   // fp32 mantissa halves ~1/256; bf16 never
    int c2 = 0;
    for (int i = threadIdx.x * 2 + 1; i < 8192; i += 512)
        if (ei[i] != 0) c2++;                      // int64 high words are 0
    atomicAdd(&h1, c1);
    atomicAdd(&h2, c2);
    __syncthreads();
    if (threadIdx.x == 0) { flags[0] = (h1 >= 8); flags[1] = (h2 < 8); }
}

// ---- K0: zero counts/cursor ----
__global__ void k0_init(int* counts, int* cursor, int N) {
    int i = blockIdx.x * blockDim.x + threadIdx.x;
    if (i <= N) counts[i] = 0;
    if (i < N) cursor[i] = 0;
}

// ---- K1: proj = x@W (VALU, 16 rows/block) + fused per-node scores ----
__global__ __launch_bounds__(256) void k1_proj(
    const void* __restrict__ x, const void* __restrict__ W,
    const void* __restrict__ a_src, const void* __restrict__ a_trg,
    const int* __restrict__ flags, unsigned short* __restrict__ projb,
    float* __restrict__ ssrc, float* __restrict__ strg, int N)
{
    __shared__ float xs[16][128];
    int f32 = flags[0];
    int t = threadIdx.x;
    int n0 = blockIdx.x * 16;
    for (int idx = t; idx < 16 * 128; idx += 256) {
        int row = idx >> 7, col = idx & 127;
        int n = n0 + row;
        if (n >= N) n = N - 1;
        xs[row][col] = ldf(x, n * 128 + col, f32);
    }
    __syncthreads();
    int j = t & 127, rg = t >> 7;
    float acc[8] = {0.f, 0.f, 0.f, 0.f, 0.f, 0.f, 0.f, 0.f};
    for (int k = 0; k < 128; k++) {
        float w = ldf(W, k * 128 + j, f32);
#pragma unroll
        for (int rr = 0; rr < 8; rr++)
            acc[rr] = fmaf(xs[rg * 8 + rr][k], w, acc[rr]);
    }
#pragma unroll
    for (int rr = 0; rr < 8; rr++) {
        int n = n0 + rg * 8 + rr;
        if (n < N) projb[(size_t)n * 128 + j] = f2bf(acc[rr]);
    }
    float av = ldf(a_src, j, f32);
    float bv = ldf(a_trg, j, f32);
    float ps[8], pt[8];
#pragma unroll
    for (int rr = 0; rr < 8; rr++) { ps[rr] = acc[rr] * av; pt[rr] = acc[rr] * bv; }
#pragma unroll
    for (int k = 1; k < 32; k <<= 1) {
#pragma unroll
        for (int rr = 0; rr < 8; rr++) {
            ps[rr] += __shfl_xor(ps[rr], k, 32);
            pt[rr] += __shfl_xor(pt[rr], k, 32);
        }
    }
    if ((t & 31) == 0) {
        int h = (t >> 5) & 3;
#pragma unroll
        for (int rr = 0; rr < 8; rr++) {
            int n = n0 + rg * 8 + rr;
            if (n < N) {
                ssrc[n * 4 + h] = ps[rr];
                strg[n * 4 + h] = pt[rr];
            }
        }
    }
}

__device__ inline void edge_scores(const float* ssrc, const float* strg,
                                   int src, int trg, float* v) {
    float4 a = *(const float4*)(ssrc + (size_t)src * 4);
    float4 b = *(const float4*)(strg + (size_t)trg * 4);
    v[0] = a.x + b.x; v[1] = a.y + b.y; v[2] = a.z + b.z; v[3] = a.w + b.w;
#pragma unroll
    for (int h = 0; h < 4; h++) v[h] = v[h] > 0.f ? v[h] : 0.2f * v[h];
}

// ---- KE: in-degree histogram + per-block max (NO same-address atomics) ----
__global__ __launch_bounds__(256) void kE_count_max(
    const int* __restrict__ ei, const float* __restrict__ ssrc,
    const float* __restrict__ strg, const int* __restrict__ flags,
    int* __restrict__ counts, float* __restrict__ blockmax, int E, int N)
{
    int e64 = flags[1];
    int e = blockIdx.x * 256 + threadIdx.x;
    float m = -3.0e38f;
    if (e < E) {
        int src = min(max(lde(ei, e, e64), 0), N - 1);
        int trg = min(max(lde(ei, E + e, e64), 0), N - 1);
        atomicAdd(&counts[trg], 1);
        float v[4];
        edge_scores(ssrc, strg, src, trg, v);
        m = fmaxf(fmaxf(v[0], v[1]), fmaxf(v[2], v[3]));
    }
#pragma unroll
    for (int k = 1; k < 64; k <<= 1) m = fmaxf(m, __shfl_xor(m, k, 64));
    __shared__ float wm[4];
    if ((threadIdx.x & 63) == 0) wm[threadIdx.x >> 6] = m;
    __syncthreads();
    if (threadIdx.x == 0)
        blockmax[blockIdx.x] = fmaxf(fmaxf(wm[0], wm[1]), fmaxf(wm[2], wm[3]));
}

// ---- KR: reduce per-block maxima -> Mval (single block) ----
__global__ __launch_bounds__(256) void kR_reduce(
    const float* __restrict__ blockmax, float* __restrict__ Mval, int nb)
{
    float m = -3.0e38f;
    for (int i = threadIdx.x; i < nb; i += 256) m = fmaxf(m, blockmax[i]);
#pragma unroll
    for (int k = 1; k < 64; k <<= 1) m = fmaxf(m, __shfl_xor(m, k, 64));
    __shared__ float wm[4];
    if ((threadIdx.x & 63) == 0) wm[threadIdx.x >> 6] = m;
    __syncthreads();
    if (threadIdx.x == 0)
        *Mval = fmaxf(fmaxf(wm[0], wm[1]), fmaxf(wm[2], wm[3]));
}

// ---- K2b: exclusive scan counts -> offsets (single block) ----
__global__ __launch_bounds__(1024) void k2b_scan(
    const int* __restrict__ counts, int* __restrict__ offsets, int NP1)
{
    __shared__ int lds[1024];
    int t = threadIdx.x;
    int C = (NP1 + 1023) >> 10;
    int lo = t * C, hi = min(lo + C, NP1);
    int s = 0;
    for (int i = lo; i < hi; i++) s += counts[i];
    lds[t] = s;
    __syncthreads();
    int incl = s;
    for (int st = 1; st < 1024; st <<= 1) {
        int add = (t >= st) ? lds[t - st] : 0;
        __syncthreads();
        incl += add;
        lds[t] = incl;
        __syncthreads();
    }
    int run = incl - s;
    for (int i = lo; i < hi; i++) { offsets[i] = run; run += counts[i]; }
}

// ---- K2c (eexp variant): CSR scatter + per-edge exp(leaky(score)-M) ----
__global__ __launch_bounds__(256) void k2c_scatter_exp(
    const int* __restrict__ ei, const int* __restrict__ offsets,
    const float* __restrict__ ssrc, const float* __restrict__ strg,
    const int* __restrict__ flags, const float* __restrict__ Mval,
    int* __restrict__ cursor, int* __restrict__ esrc, float4* __restrict__ eexp,
    int E, int N)
{
    int e64 = flags[1];
    int e = blockIdx.x * 256 + threadIdx.x;
    if (e >= E) return;
    float M = *Mval;
    int src = min(max(lde(ei, e, e64), 0), N - 1);
    int trg = min(max(lde(ei, E + e, e64), 0), N - 1);
    int pos = offsets[trg] + atomicAdd(&cursor[trg], 1);
    if (pos < 0 || pos >= E) return;
    esrc[pos] = src;
    float v[4];
    edge_scores(ssrc, strg, src, trg, v);
    eexp[pos] = make_float4(__expf(v[0] - M), __expf(v[1] - M),
                            __expf(v[2] - M), __expf(v[3] - M));
}

// ---- K2c (fallback, no eexp) ----
__global__ __launch_bounds__(256) void k2c_scatter(
    const int* __restrict__ ei, const int* __restrict__ offsets,
    const int* __restrict__ flags, int* __restrict__ cursor,
    int* __restrict__ esrc, int E, int N)
{
    int e64 = flags[1];
    int e = blockIdx.x * 256 + threadIdx.x;
    if (e >= E) return;
    int src = min(max(lde(ei, e, e64), 0), N - 1);
    int trg = min(max(lde(ei, E + e, e64), 0), N - 1);
    int pos = offsets[trg] + atomicAdd(&cursor[trg], 1);
    if (pos >= 0 && pos < E) esrc[pos] = src;
}

// ---- K3 (eexp variant): coalesced eexp reads; no score gathers ----
__global__ __launch_bounds__(256) void k3_agg_e(
    const int* __restrict__ offsets, const int* __restrict__ esrc,
    const float4* __restrict__ eexp, const unsigned short* __restrict__ projb,
    const void* __restrict__ x, const void* __restrict__ bias,
    const int* __restrict__ flags, float* __restrict__ out, int N, int E)
{
    int w = threadIdx.x >> 6;
    int lane = threadIdx.x & 63;
    int n = blockIdx.x * 4 + w;
    int f32 = flags[0];
    bool valid = (n < N);
    int nc = valid ? n : N - 1;
    int off = offsets[nc];
    int d = offsets[nc + 1] - off;
    d = max(0, min(d, E));
    if (!valid) d = 0;

    // Pass A: denominators from coalesced eexp
    float den[4] = {0.f, 0.f, 0.f, 0.f};
    for (int i = lane; i < d; i += 64) {
        float4 ev = eexp[off + i];
        den[0] += ev.x; den[1] += ev.y; den[2] += ev.z; den[3] += ev.w;
    }
#pragma unroll
    for (int k = 1; k < 64; k <<= 1)
#pragma unroll
        for (int h = 0; h < 4; h++) den[h] += __shfl_xor(den[h], k, 64);
    float inv[4];
#pragma unroll
    for (int h = 0; h < 4; h++) inv[h] = 1.0f / (den[h] + 1e-16f);

    __shared__ int dmax_s[4];
    if (lane == 0) dmax_s[w] = d;
    __syncthreads();
    int dmx = max(max(dmax_s[0], dmax_s[1]), max(dmax_s[2], dmax_s[3]));

    __shared__ int lsrc[4][64];
    __shared__ float latt[4][64 * 5];
    float acc0 = 0.f, acc1 = 0.f;
    int h01 = lane >> 4;
    for (int base = 0; base < dmx; base += 64) {
        int cd = min(64, d - base);
        if (lane < cd) {
            int s = min(max(esrc[off + base + lane], 0), N - 1);
            lsrc[w][lane] = s;
            float4 ev = eexp[off + base + lane];
            latt[w][lane * 5 + 0] = ev.x * inv[0];
            latt[w][lane * 5 + 1] = ev.y * inv[1];
            latt[w][lane * 5 + 2] = ev.z * inv[2];
            latt[w][lane * 5 + 3] = ev.w * inv[3];
        }
        __syncthreads();
        for (int k = 0; k < cd; k++) {
            int s = lsrc[w][k];
            float att = latt[w][k * 5 + h01];
            unsigned p = *(const unsigned*)(projb + (size_t)s * 128 + lane * 2);
            acc0 = fmaf(bf2f((unsigned short)(p & 0xffffu)), att, acc0);
            acc1 = fmaf(bf2f((unsigned short)(p >> 16)), att, acc1);
        }
        __syncthreads();
    }

    if (!valid) return;
    int j0 = lane * 2;
    float o0 = acc0 + ldf(x, n * 128 + j0, f32) + ldf(bias, j0, f32);
    float o1 = acc1 + ldf(x, n * 128 + j0 + 1, f32) + ldf(bias, j0 + 1, f32);
    o0 = o0 > 0.f ? o0 : __expf(o0) - 1.f;
    o1 = o1 > 0.f ? o1 : __expf(o1) - 1.f;
    out[(size_t)n * 128 + j0]     = o0;
    out[(size_t)n * 128 + j0 + 1] = o1;
}

// ---- K3 (fallback, gathers scores) ----
__global__ __launch_bounds__(256) void k3_agg_g(
    const int* __restrict__ offsets, const int* __restrict__ esrc,
    const float* __restrict__ ssrc, const float* __restrict__ strg,
    const unsigned short* __restrict__ projb, const void* __restrict__ x,
    const void* __restrict__ bias, const int* __restrict__ flags,
    const float* __restrict__ Mval, float* __restrict__ out, int N, int E)
{
    int w = threadIdx.x >> 6;
    int lane = threadIdx.x & 63;
    int n = blockIdx.x * 4 + w;
    int f32 = flags[0];
    bool valid = (n < N);
    int nc = valid ? n : N - 1;
    int off = offsets[nc];
    int d = offsets[nc + 1] - off;
    d = max(0, min(d, E));
    if (!valid) d = 0;
    float M = *Mval;
    float4 stv = *(const float4*)(strg + (size_t)nc * 4);
    float st[4] = {stv.x, stv.y, stv.z, stv.w};
    float den[4] = {0.f, 0.f, 0.f, 0.f};
    for (int i = lane; i < d; i += 64) {
        int s = min(max(esrc[off + i], 0), N - 1);
        float4 ssv = *(const float4*)(ssrc + (size_t)s * 4);
        float sv[4] = {ssv.x, ssv.y, ssv.z, ssv.w};
#pragma unroll
        for (int h = 0; h < 4; h++) {
            float v = sv[h] + st[h];
            v = v > 0.f ? v : 0.2f * v;
            den[h] += __expf(v - M);
        }
    }
#pragma unroll
    for (int k = 1; k < 64; k <<= 1)
#pragma unroll
        for (int h = 0; h < 4; h++) den[h] += __shfl_xor(den[h], k, 64);
    float inv[4];
#pragma unroll
    for (int h = 0; h < 4; h++) inv[h] = 1.0f / (den[h] + 1e-16f);
    __shared__ int dmax_s[4];
    if (lane == 0) dmax_s[w] = d;
    __syncthreads();
    int dmx = max(max(dmax_s[0], dmax_s[1]), max(dmax_s[2], dmax_s[3]));
    __shared__ int lsrc[4][64];
    __shared__ float latt[4][64 * 5];
    float acc0 = 0.f, acc1 = 0.f;
    int h01 = lane >> 4;
    for (int base = 0; base < dmx; base += 64) {
        int cd = min(64, d - base);
        if (lane < cd) {
            int s = min(max(esrc[off + base + lane], 0), N - 1);
            lsrc[w][lane] = s;
            float4 ssv = *(const float4*)(ssrc + (size_t)s * 4);
            float sv[4] = {ssv.x, ssv.y, ssv.z, ssv.w};
#pragma unroll
            for (int h = 0; h < 4; h++) {
                float v = sv[h] + st[h];
                v = v > 0.f ? v : 0.2f * v;
                latt[w][lane * 5 + h] = __expf(v - M) * inv[h];
            }
        }
        __syncthreads();
        for (int k = 0; k < cd; k++) {
            int s = lsrc[w][k];
            float att = latt[w][k * 5 + h01];
            unsigned p = *(const unsigned*)(projb + (size_t)s * 128 + lane * 2);
            acc0 = fmaf(bf2f((unsigned short)(p & 0xffffu)), att, acc0);
            acc1 = fmaf(bf2f((unsigned short)(p >> 16)), att, acc1);
        }
        __syncthreads();
    }
    if (!valid) return;
    int j0 = lane * 2;
    float o0 = acc0 + ldf(x, n * 128 + j0, f32) + ldf(bias, j0, f32);
    float o1 = acc1 + ldf(x, n * 128 + j0 + 1, f32) + ldf(bias, j0 + 1, f32);
    o0 = o0 > 0.f ? o0 : __expf(o0) - 1.f;
    o1 = o1 > 0.f ? o1 : __expf(o1) - 1.f;
    out[(size_t)n * 128 + j0]     = o0;
    out[(size_t)n * 128 + j0 + 1] = o1;
}

extern "C" void kernel_launch(void* const* d_in, const int* in_sizes, int n_in,
                              void* d_out, int out_size, void* d_ws, size_t ws_size,
                              hipStream_t stream)
{
    const void* x     = d_in[0];
    const int*  ei    = (const int*)d_in[1];
    const void* W     = d_in[2];
    const void* a_src = d_in[3];
    const void* a_trg = d_in[4];
    const void* bias  = d_in[5];
    float* out = (float*)d_out;
    int N = in_sizes[0] / 128;
    int E = N * 16;
    if (in_sizes[1] / 2 < E) E = in_sizes[1] / 2;
    int nbE = (E + 255) / 256;

    char* ws = (char*)d_ws;
    size_t o = 0;
    auto alloc = [&](size_t bytes) {
        size_t r = o;
        o = (o + bytes + 255) & ~(size_t)255;
        return r;
    };
    int* flags = (int*)(ws + alloc(256));
    unsigned short* projb = (unsigned short*)(ws + alloc((size_t)N * 128 * 2));
    float* ssrc  = (float*)(ws + alloc((size_t)N * 4 * 4));
    float* strg  = (float*)(ws + alloc((size_t)N * 4 * 4));
    float* Mval  = (float*)(ws + alloc(256));
    int* counts  = (int*)(ws + alloc((size_t)(N + 1) * 4));
    int* offsets = (int*)(ws + alloc((size_t)(N + 1) * 4));
    int* cursor  = (int*)(ws + alloc((size_t)N * 4));
    int* esrc    = (int*)(ws + alloc((size_t)E * 4));
    float* blockmax = (float*)(ws + alloc((size_t)nbE * 4));
    size_t base = o;
    size_t need_eexp = base + (size_t)E * 16 + 256;

    k_det<<<1, 256, 0, stream>>>(x, ei, flags);
    k0_init<<<(N + 256) / 256, 256, 0, stream>>>(counts, cursor, N);
    k1_proj<<<(N + 15) / 16, 256, 0, stream>>>(x, W, a_src, a_trg, flags, projb, ssrc, strg, N);
    kE_count_max<<<nbE, 256, 0, stream>>>(ei, ssrc, strg, flags, counts, blockmax, E, N);
    kR_reduce<<<1, 256, 0, stream>>>(blockmax, Mval, nbE);
    k2b_scan<<<1, 1024, 0, stream>>>(counts, offsets, N + 1);

    if (ws_size >= need_eexp) {
        float4* eexp = (float4*)(ws + alloc((size_t)E * 16));
        k2c_scatter_exp<<<nbE, 256, 0, stream>>>(ei, offsets, ssrc, strg, flags, Mval,
                                                 cursor, esrc, eexp, E, N);
        k3_agg_e<<<(N + 3) / 4, 256, 0, stream>>>(offsets, esrc, eexp, projb, x, bias,
                                                  flags, out, N, E);
    } else {
        k2c_scatter<<<nbE, 256, 0, stream>>>(ei, offsets, flags, cursor, esrc, E, N);
        k3_agg_g<<<(N + 3) / 4, 256, 0, stream>>>(offsets, esrc, ssrc, strg, projb, x, bias,
                                                  flags, Mval, out, N, E);
    }
}

// Round 8
// 310.096 us; speedup vs baseline: 2.7763x; 1.2164x over previous
//
#include <hip/hip_runtime.h>
#include <stdint.h>

__device__ inline float bf2f(unsigned short b) {
    unsigned u = ((unsigned)b) << 16;
    return __builtin_bit_cast(float, u);
}
__device__ inline unsigned short f2bf(float f) {
    unsigned u = __builtin_bit_cast(unsigned, f);
    unsigned r = (u + 0x7fffu + ((u >> 16) & 1u)) >> 16;
    return (unsigned short)r;
}
__device__ inline float ldf(const void* p, int i, int f32) {
    return f32 ? ((const float*)p)[i] : bf2f(((const unsigned short*)p)[i]);
}
__device__ inline int lde(const int* ei, int idx, int is64) {
    return is64 ? ei[2 * idx] : ei[idx];
}

// ---- K_det: input dtype layouts (deterministic, every launch) ----
__global__ void k_det(const void* x, const int* ei, int* flags) {
    __shared__ int h1, h2;
    if (threadIdx.x == 0) { h1 = 0; h2 = 0; }
    __syncthreads();
    const unsigned short* xs = (const unsigned short*)x;
    int c1 = 0;
    for (int i = threadIdx.x * 2; i < 65536; i += 512)
        if ((xs[i] & 0x7f80u) == 0x7f80u) c1++;   // fp32 mantissa halves ~1/256; bf16 never
    int c2 = 0;
    for (int i = threadIdx.x * 2 + 1; i < 8192; i += 512)
        if (ei[i] != 0) c2++;                      // int64 high words are 0
    atomicAdd(&h1, c1);
    atomicAdd(&h2, c2);
    __syncthreads();
    if (threadIdx.x == 0) { flags[0] = (h1 >= 8); flags[1] = (h2 < 8); }
}

// ---- K0: zero counts/cursor ----
__global__ void k0_init(int* counts, int* cursor, int N) {
    int i = blockIdx.x * blockDim.x + threadIdx.x;
    if (i <= N) counts[i] = 0;
    if (i < N) cursor[i] = 0;
}

// ---- K1: proj = x@W (VALU, 16 rows/block) + fused per-node scores ----
__global__ __launch_bounds__(256) void k1_proj(
    const void* __restrict__ x, const void* __restrict__ W,
    const void* __restrict__ a_src, const void* __restrict__ a_trg,
    const int* __restrict__ flags, unsigned short* __restrict__ projb,
    float* __restrict__ ssrc, float* __restrict__ strg, int N)
{
    __shared__ float xs[16][128];
    int f32 = flags[0];
    int t = threadIdx.x;
    int n0 = blockIdx.x * 16;
    for (int idx = t; idx < 16 * 128; idx += 256) {
        int row = idx >> 7, col = idx & 127;
        int n = n0 + row;
        if (n >= N) n = N - 1;
        xs[row][col] = ldf(x, n * 128 + col, f32);
    }
    __syncthreads();
    int j = t & 127, rg = t >> 7;
    float acc[8] = {0.f, 0.f, 0.f, 0.f, 0.f, 0.f, 0.f, 0.f};
    for (int k = 0; k < 128; k++) {
        float w = ldf(W, k * 128 + j, f32);
#pragma unroll
        for (int rr = 0; rr < 8; rr++)
            acc[rr] = fmaf(xs[rg * 8 + rr][k], w, acc[rr]);
    }
#pragma unroll
    for (int rr = 0; rr < 8; rr++) {
        int n = n0 + rg * 8 + rr;
        if (n < N) projb[(size_t)n * 128 + j] = f2bf(acc[rr]);
    }
    float av = ldf(a_src, j, f32);
    float bv = ldf(a_trg, j, f32);
    float ps[8], pt[8];
#pragma unroll
    for (int rr = 0; rr < 8; rr++) { ps[rr] = acc[rr] * av; pt[rr] = acc[rr] * bv; }
#pragma unroll
    for (int k = 1; k < 32; k <<= 1) {
#pragma unroll
        for (int rr = 0; rr < 8; rr++) {
            ps[rr] += __shfl_xor(ps[rr], k, 32);
            pt[rr] += __shfl_xor(pt[rr], k, 32);
        }
    }
    if ((t & 31) == 0) {
        int h = (t >> 5) & 3;
#pragma unroll
        for (int rr = 0; rr < 8; rr++) {
            int n = n0 + rg * 8 + rr;
            if (n < N) {
                ssrc[n * 4 + h] = ps[rr];
                strg[n * 4 + h] = pt[rr];
            }
        }
    }
}

__device__ inline void edge_scores(const float* ssrc, const float* strg,
                                   int src, int trg, float* v) {
    float4 a = *(const float4*)(ssrc + (size_t)src * 4);
    float4 b = *(const float4*)(strg + (size_t)trg * 4);
    v[0] = a.x + b.x; v[1] = a.y + b.y; v[2] = a.z + b.z; v[3] = a.w + b.w;
#pragma unroll
    for (int h = 0; h < 4; h++) v[h] = v[h] > 0.f ? v[h] : 0.2f * v[h];
}

// ---- KE: in-degree histogram + per-block max (no same-address atomics) ----
__global__ __launch_bounds__(256) void kE_count_max(
    const int* __restrict__ ei, const float* __restrict__ ssrc,
    const float* __restrict__ strg, const int* __restrict__ flags,
    int* __restrict__ counts, float* __restrict__ blockmax, int E, int N)
{
    int e64 = flags[1];
    int e = blockIdx.x * 256 + threadIdx.x;
    float m = -3.0e38f;
    if (e < E) {
        int src = min(max(lde(ei, e, e64), 0), N - 1);
        int trg = min(max(lde(ei, E + e, e64), 0), N - 1);
        atomicAdd(&counts[trg], 1);
        float v[4];
        edge_scores(ssrc, strg, src, trg, v);
        m = fmaxf(fmaxf(v[0], v[1]), fmaxf(v[2], v[3]));
    }
#pragma unroll
    for (int k = 1; k < 64; k <<= 1) m = fmaxf(m, __shfl_xor(m, k, 64));
    __shared__ float wm[4];
    if ((threadIdx.x & 63) == 0) wm[threadIdx.x >> 6] = m;
    __syncthreads();
    if (threadIdx.x == 0)
        blockmax[blockIdx.x] = fmaxf(fmaxf(wm[0], wm[1]), fmaxf(wm[2], wm[3]));
}

// ---- S1: per-block sums of counts (coalesced) ----
__global__ __launch_bounds__(256) void kS1_psum(
    const int* __restrict__ counts, int* __restrict__ partials, int NP1)
{
    int idx = blockIdx.x * 256 + threadIdx.x;
    int v = (idx < NP1) ? counts[idx] : 0;
#pragma unroll
    for (int k = 1; k < 64; k <<= 1) v += __shfl_xor(v, k, 64);
    __shared__ int wsum[4];
    if ((threadIdx.x & 63) == 0) wsum[threadIdx.x >> 6] = v;
    __syncthreads();
    if (threadIdx.x == 0)
        partials[blockIdx.x] = wsum[0] + wsum[1] + wsum[2] + wsum[3];
}

// ---- S2: exclusive scan of partials (<=256) + Mval reduction (1 block) ----
__global__ __launch_bounds__(256) void kS2_scanp(
    int* __restrict__ partials, int nb,
    const float* __restrict__ blockmax, float* __restrict__ Mval, int nbm)
{
    int t = threadIdx.x;
    if (nb <= 256) {
        __shared__ int lds[256];
        int v = (t < nb) ? partials[t] : 0;
        lds[t] = v;
        __syncthreads();
        int incl = v;
        for (int st = 1; st < 256; st <<= 1) {
            int add = (t >= st) ? lds[t - st] : 0;
            __syncthreads();
            incl += add;
            lds[t] = incl;
            __syncthreads();
        }
        if (t < nb) partials[t] = incl - v;
    } else if (t == 0) {          // safety fallback, never hit at N=50000
        int run = 0;
        for (int i = 0; i < nb; i++) { int c = partials[i]; partials[i] = run; run += c; }
    }
    __syncthreads();
    float m = -3.0e38f;
    for (int i = t; i < nbm; i += 256) m = fmaxf(m, blockmax[i]);
#pragma unroll
    for (int k = 1; k < 64; k <<= 1) m = fmaxf(m, __shfl_xor(m, k, 64));
    __shared__ float wm[4];
    if ((t & 63) == 0) wm[t >> 6] = m;
    __syncthreads();
    if (t == 0) *Mval = fmaxf(fmaxf(wm[0], wm[1]), fmaxf(wm[2], wm[3]));
}

// ---- S3: per-block exclusive scan + base -> offsets (coalesced) ----
__global__ __launch_bounds__(256) void kS3_offs(
    const int* __restrict__ counts, const int* __restrict__ partials,
    int* __restrict__ offsets, int NP1)
{
    int t = threadIdx.x;
    int idx = blockIdx.x * 256 + t;
    int v = (idx < NP1) ? counts[idx] : 0;
    __shared__ int lds[256];
    lds[t] = v;
    __syncthreads();
    int incl = v;
    for (int st = 1; st < 256; st <<= 1) {
        int add = (t >= st) ? lds[t - st] : 0;
        __syncthreads();
        incl += add;
        lds[t] = incl;
        __syncthreads();
    }
    if (idx < NP1) offsets[idx] = partials[blockIdx.x] + incl - v;
}

// ---- K2c (eexp variant): CSR scatter + per-edge exp(leaky(score)-M) ----
__global__ __launch_bounds__(256) void k2c_scatter_exp(
    const int* __restrict__ ei, const int* __restrict__ offsets,
    const float* __restrict__ ssrc, const float* __restrict__ strg,
    const int* __restrict__ flags, const float* __restrict__ Mval,
    int* __restrict__ cursor, int* __restrict__ esrc, float4* __restrict__ eexp,
    int E, int N)
{
    int e64 = flags[1];
    int e = blockIdx.x * 256 + threadIdx.x;
    if (e >= E) return;
    float M = *Mval;
    int src = min(max(lde(ei, e, e64), 0), N - 1);
    int trg = min(max(lde(ei, E + e, e64), 0), N - 1);
    int pos = offsets[trg] + atomicAdd(&cursor[trg], 1);
    if (pos < 0 || pos >= E) return;
    esrc[pos] = src;
    float v[4];
    edge_scores(ssrc, strg, src, trg, v);
    eexp[pos] = make_float4(__expf(v[0] - M), __expf(v[1] - M),
                            __expf(v[2] - M), __expf(v[3] - M));
}

// ---- K2c (fallback, no eexp) ----
__global__ __launch_bounds__(256) void k2c_scatter(
    const int* __restrict__ ei, const int* __restrict__ offsets,
    const int* __restrict__ flags, int* __restrict__ cursor,
    int* __restrict__ esrc, int E, int N)
{
    int e64 = flags[1];
    int e = blockIdx.x * 256 + threadIdx.x;
    if (e >= E) return;
    int src = min(max(lde(ei, e, e64), 0), N - 1);
    int trg = min(max(lde(ei, E + e, e64), 0), N - 1);
    int pos = offsets[trg] + atomicAdd(&cursor[trg], 1);
    if (pos >= 0 && pos < E) esrc[pos] = src;
}

// ---- K3 (eexp variant): coalesced eexp reads; no score gathers ----
__global__ __launch_bounds__(256) void k3_agg_e(
    const int* __restrict__ offsets, const int* __restrict__ esrc,
    const float4* __restrict__ eexp, const unsigned short* __restrict__ projb,
    const void* __restrict__ x, const void* __restrict__ bias,
    const int* __restrict__ flags, float* __restrict__ out, int N, int E)
{
    int w = threadIdx.x >> 6;
    int lane = threadIdx.x & 63;
    int n = blockIdx.x * 4 + w;
    int f32 = flags[0];
    bool valid = (n < N);
    int nc = valid ? n : N - 1;
    int off = offsets[nc];
    int d = offsets[nc + 1] - off;
    d = max(0, min(d, E));
    if (!valid) d = 0;

    float den[4] = {0.f, 0.f, 0.f, 0.f};
    for (int i = lane; i < d; i += 64) {
        float4 ev = eexp[off + i];
        den[0] += ev.x; den[1] += ev.y; den[2] += ev.z; den[3] += ev.w;
    }
#pragma unroll
    for (int k = 1; k < 64; k <<= 1)
#pragma unroll
        for (int h = 0; h < 4; h++) den[h] += __shfl_xor(den[h], k, 64);
    float inv[4];
#pragma unroll
    for (int h = 0; h < 4; h++) inv[h] = 1.0f / (den[h] + 1e-16f);

    __shared__ int dmax_s[4];
    if (lane == 0) dmax_s[w] = d;
    __syncthreads();
    int dmx = max(max(dmax_s[0], dmax_s[1]), max(dmax_s[2], dmax_s[3]));

    __shared__ int lsrc[4][64];
    __shared__ float latt[4][64 * 5];
    float acc0 = 0.f, acc1 = 0.f;
    int h01 = lane >> 4;
    for (int base = 0; base < dmx; base += 64) {
        int cd = min(64, d - base);
        if (lane < cd) {
            int s = min(max(esrc[off + base + lane], 0), N - 1);
            lsrc[w][lane] = s;
            float4 ev = eexp[off + base + lane];
            latt[w][lane * 5 + 0] = ev.x * inv[0];
            latt[w][lane * 5 + 1] = ev.y * inv[1];
            latt[w][lane * 5 + 2] = ev.z * inv[2];
            latt[w][lane * 5 + 3] = ev.w * inv[3];
        }
        __syncthreads();
        for (int k = 0; k < cd; k++) {
            int s = lsrc[w][k];
            float att = latt[w][k * 5 + h01];
            unsigned p = *(const unsigned*)(projb + (size_t)s * 128 + lane * 2);
            acc0 = fmaf(bf2f((unsigned short)(p & 0xffffu)), att, acc0);
            acc1 = fmaf(bf2f((unsigned short)(p >> 16)), att, acc1);
        }
        __syncthreads();
    }

    if (!valid) return;
    int j0 = lane * 2;
    float o0 = acc0 + ldf(x, n * 128 + j0, f32) + ldf(bias, j0, f32);
    float o1 = acc1 + ldf(x, n * 128 + j0 + 1, f32) + ldf(bias, j0 + 1, f32);
    o0 = o0 > 0.f ? o0 : __expf(o0) - 1.f;
    o1 = o1 > 0.f ? o1 : __expf(o1) - 1.f;
    out[(size_t)n * 128 + j0]     = o0;
    out[(size_t)n * 128 + j0 + 1] = o1;
}

// ---- K3 (fallback, gathers scores) ----
__global__ __launch_bounds__(256) void k3_agg_g(
    const int* __restrict__ offsets, const int* __restrict__ esrc,
    const float* __restrict__ ssrc, const float* __restrict__ strg,
    const unsigned short* __restrict__ projb, const void* __restrict__ x,
    const void* __restrict__ bias, const int* __restrict__ flags,
    const float* __restrict__ Mval, float* __restrict__ out, int N, int E)
{
    int w = threadIdx.x >> 6;
    int lane = threadIdx.x & 63;
    int n = blockIdx.x * 4 + w;
    int f32 = flags[0];
    bool valid = (n < N);
    int nc = valid ? n : N - 1;
    int off = offsets[nc];
    int d = offsets[nc + 1] - off;
    d = max(0, min(d, E));
    if (!valid) d = 0;
    float M = *Mval;
    float4 stv = *(const float4*)(strg + (size_t)nc * 4);
    float st[4] = {stv.x, stv.y, stv.z, stv.w};
    float den[4] = {0.f, 0.f, 0.f, 0.f};
    for (int i = lane; i < d; i += 64) {
        int s = min(max(esrc[off + i], 0), N - 1);
        float4 ssv = *(const float4*)(ssrc + (size_t)s * 4);
        float sv[4] = {ssv.x, ssv.y, ssv.z, ssv.w};
#pragma unroll
        for (int h = 0; h < 4; h++) {
            float v = sv[h] + st[h];
            v = v > 0.f ? v : 0.2f * v;
            den[h] += __expf(v - M);
        }
    }
#pragma unroll
    for (int k = 1; k < 64; k <<= 1)
#pragma unroll
        for (int h = 0; h < 4; h++) den[h] += __shfl_xor(den[h], k, 64);
    float inv[4];
#pragma unroll
    for (int h = 0; h < 4; h++) inv[h] = 1.0f / (den[h] + 1e-16f);
    __shared__ int dmax_s[4];
    if (lane == 0) dmax_s[w] = d;
    __syncthreads();
    int dmx = max(max(dmax_s[0], dmax_s[1]), max(dmax_s[2], dmax_s[3]));
    __shared__ int lsrc[4][64];
    __shared__ float latt[4][64 * 5];
    float acc0 = 0.f, acc1 = 0.f;
    int h01 = lane >> 4;
    for (int base = 0; base < dmx; base += 64) {
        int cd = min(64, d - base);
        if (lane < cd) {
            int s = min(max(esrc[off + base + lane], 0), N - 1);
            lsrc[w][lane] = s;
            float4 ssv = *(const float4*)(ssrc + (size_t)s * 4);
            float sv[4] = {ssv.x, ssv.y, ssv.z, ssv.w};
#pragma unroll
            for (int h = 0; h < 4; h++) {
                float v = sv[h] + st[h];
                v = v > 0.f ? v : 0.2f * v;
                latt[w][lane * 5 + h] = __expf(v - M) * inv[h];
            }
        }
        __syncthreads();
        for (int k = 0; k < cd; k++) {
            int s = lsrc[w][k];
            float att = latt[w][k * 5 + h01];
            unsigned p = *(const unsigned*)(projb + (size_t)s * 128 + lane * 2);
            acc0 = fmaf(bf2f((unsigned short)(p & 0xffffu)), att, acc0);
            acc1 = fmaf(bf2f((unsigned short)(p >> 16)), att, acc1);
        }
        __syncthreads();
    }
    if (!valid) return;
    int j0 = lane * 2;
    float o0 = acc0 + ldf(x, n * 128 + j0, f32) + ldf(bias, j0, f32);
    float o1 = acc1 + ldf(x, n * 128 + j0 + 1, f32) + ldf(bias, j0 + 1, f32);
    o0 = o0 > 0.f ? o0 : __expf(o0) - 1.f;
    o1 = o1 > 0.f ? o1 : __expf(o1) - 1.f;
    out[(size_t)n * 128 + j0]     = o0;
    out[(size_t)n * 128 + j0 + 1] = o1;
}

extern "C" void kernel_launch(void* const* d_in, const int* in_sizes, int n_in,
                              void* d_out, int out_size, void* d_ws, size_t ws_size,
                              hipStream_t stream)
{
    const void* x     = d_in[0];
    const int*  ei    = (const int*)d_in[1];
    const void* W     = d_in[2];
    const void* a_src = d_in[3];
    const void* a_trg = d_in[4];
    const void* bias  = d_in[5];
    float* out = (float*)d_out;
    int N = in_sizes[0] / 128;
    int E = N * 16;
    if (in_sizes[1] / 2 < E) E = in_sizes[1] / 2;
    int nbE = (E + 255) / 256;
    int NP1 = N + 1;
    int nbS = (NP1 + 255) / 256;

    char* ws = (char*)d_ws;
    size_t o = 0;
    auto alloc = [&](size_t bytes) {
        size_t r = o;
        o = (o + bytes + 255) & ~(size_t)255;
        return r;
    };
    int* flags = (int*)(ws + alloc(256));
    unsigned short* projb = (unsigned short*)(ws + alloc((size_t)N * 128 * 2));
    float* ssrc  = (float*)(ws + alloc((size_t)N * 4 * 4));
    float* strg  = (float*)(ws + alloc((size_t)N * 4 * 4));
    float* Mval  = (float*)(ws + alloc(256));
    int* counts  = (int*)(ws + alloc((size_t)NP1 * 4));
    int* offsets = (int*)(ws + alloc((size_t)NP1 * 4));
    int* cursor  = (int*)(ws + alloc((size_t)N * 4));
    int* esrc    = (int*)(ws + alloc((size_t)E * 4));
    float* blockmax = (float*)(ws + alloc((size_t)nbE * 4));
    int* partials = (int*)(ws + alloc((size_t)nbS * 4));
    size_t base = o;
    size_t need_eexp = base + (size_t)E * 16 + 256;

    k_det<<<1, 256, 0, stream>>>(x, ei, flags);
    k0_init<<<(N + 256) / 256, 256, 0, stream>>>(counts, cursor, N);
    k1_proj<<<(N + 15) / 16, 256, 0, stream>>>(x, W, a_src, a_trg, flags, projb, ssrc, strg, N);
    kE_count_max<<<nbE, 256, 0, stream>>>(ei, ssrc, strg, flags, counts, blockmax, E, N);
    kS1_psum<<<nbS, 256, 0, stream>>>(counts, partials, NP1);
    kS2_scanp<<<1, 256, 0, stream>>>(partials, nbS, blockmax, Mval, nbE);
    kS3_offs<<<nbS, 256, 0, stream>>>(counts, partials, offsets, NP1);

    if (ws_size >= need_eexp) {
        float4* eexp = (float4*)(ws + alloc((size_t)E * 16));
        k2c_scatter_exp<<<nbE, 256, 0, stream>>>(ei, offsets, ssrc, strg, flags, Mval,
                                                 cursor, esrc, eexp, E, N);
        k3_agg_e<<<(N + 3) / 4, 256, 0, stream>>>(offsets, esrc, eexp, projb, x, bias,
                                                  flags, out, N, E);
    } else {
        k2c_scatter<<<nbE, 256, 0, stream>>>(ei, offsets, flags, cursor, esrc, E, N);
        k3_agg_g<<<(N + 3) / 4, 256, 0, stream>>>(offsets, esrc, ssrc, strg, projb, x, bias,
                                                  flags, Mval, out, N, E);
    }
}

// Round 9
// 297.127 us; speedup vs baseline: 2.8975x; 1.0436x over previous
//
#include <hip/hip_runtime.h>
#include <stdint.h>

typedef __attribute__((ext_vector_type(8))) short short8;
typedef __attribute__((ext_vector_type(4))) float floatx4;

__device__ inline float bf2f(unsigned short b) {
    unsigned u = ((unsigned)b) << 16;
    return __builtin_bit_cast(float, u);
}
__device__ inline unsigned short f2bf(float f) {
    unsigned u = __builtin_bit_cast(unsigned, f);
    unsigned r = (u + 0x7fffu + ((u >> 16) & 1u)) >> 16;
    return (unsigned short)r;
}
__device__ inline float ldf(const void* p, int i, int f32) {
    return f32 ? ((const float*)p)[i] : bf2f(((const unsigned short*)p)[i]);
}
__device__ inline int lde(const int* ei, int idx, int is64) {
    return is64 ? ei[2 * idx] : ei[idx];
}

// ---- K_det: input dtype layouts (deterministic, every launch) ----
__global__ void k_det(const void* x, const int* ei, int* flags) {
    __shared__ int h1, h2;
    if (threadIdx.x == 0) { h1 = 0; h2 = 0; }
    __syncthreads();
    const unsigned short* xs = (const unsigned short*)x;
    int c1 = 0;
    for (int i = threadIdx.x * 2; i < 65536; i += 512)
        if ((xs[i] & 0x7f80u) == 0x7f80u) c1++;   // fp32 mantissa halves ~1/256; bf16 never
    int c2 = 0;
    for (int i = threadIdx.x * 2 + 1; i < 8192; i += 512)
        if (ei[i] != 0) c2++;                      // int64 high words are 0
    atomicAdd(&h1, c1);
    atomicAdd(&h2, c2);
    __syncthreads();
    if (threadIdx.x == 0) { flags[0] = (h1 >= 8); flags[1] = (h2 < 8); }
}

// ---- K0: zero counts/cursor ----
__global__ void k0_init(int* counts, int* cursor, int N) {
    int i = blockIdx.x * blockDim.x + threadIdx.x;
    if (i <= N) counts[i] = 0;
    if (i < N) cursor[i] = 0;
}

// ---- K1: proj = x@W via bf16x3 MFMA (validated bit-exact vs VALU in r2-r4)
//      + fused per-node scores. Hi/lo split done in-kernel.
__global__ __launch_bounds__(256) void k1_gemm(
    const void* __restrict__ x, const void* __restrict__ W,
    const void* __restrict__ a_src, const void* __restrict__ a_trg,
    const int* __restrict__ flags, unsigned short* __restrict__ projb,
    float* __restrict__ ssrc, float* __restrict__ strg, int N)
{
    __shared__ __align__(16) unsigned short WT[128 * 136];  // 34.8 KB, b128 2-way (free)
    int t = threadIdx.x;
    int f32 = flags[0];
    // phase-1 stage: WT[n][k] = bf16_hi(W[k][n])
    for (int idx = t; idx < 128 * 128; idx += 256) {
        int f = idx >> 7, j = idx & 127;
        WT[j * 136 + f] = f2bf(ldf(W, idx, f32));
    }
    __syncthreads();
    int wave = t >> 6, lane = t & 63;
    int col = lane & 15, quad = lane >> 4;
    int row0 = blockIdx.x * 64 + wave * 16;
    int m = row0 + col;
    if (m >= N) m = N - 1;
    // A frags: A[m=col][k=kb*32+quad*8+j]; hi/lo split in registers
    short8 ah[4], al[4];
#pragma unroll
    for (int kb = 0; kb < 4; kb++) {
#pragma unroll
        for (int j = 0; j < 8; j++) {
            float v = ldf(x, m * 128 + kb * 32 + quad * 8 + j, f32);
            unsigned short h = f2bf(v);
            ah[kb][j] = (short)h;
            al[kb][j] = (short)f2bf(v - bf2f(h));
        }
    }
    floatx4 acc[8];
#pragma unroll
    for (int c = 0; c < 8; c++) acc[c] = (floatx4){0.f, 0.f, 0.f, 0.f};
    // phase-1 compute: xh@Wh + xl@Wh
#pragma unroll
    for (int c = 0; c < 8; c++) {
        const short8* bp = (const short8*)(&WT[(c * 16 + col) * 136 + quad * 8]);
        short8 b0 = bp[0], b1 = bp[4], b2 = bp[8], b3 = bp[12];
        acc[c] = __builtin_amdgcn_mfma_f32_16x16x32_bf16(ah[0], b0, acc[c], 0, 0, 0);
        acc[c] = __builtin_amdgcn_mfma_f32_16x16x32_bf16(ah[1], b1, acc[c], 0, 0, 0);
        acc[c] = __builtin_amdgcn_mfma_f32_16x16x32_bf16(ah[2], b2, acc[c], 0, 0, 0);
        acc[c] = __builtin_amdgcn_mfma_f32_16x16x32_bf16(ah[3], b3, acc[c], 0, 0, 0);
        acc[c] = __builtin_amdgcn_mfma_f32_16x16x32_bf16(al[0], b0, acc[c], 0, 0, 0);
        acc[c] = __builtin_amdgcn_mfma_f32_16x16x32_bf16(al[1], b1, acc[c], 0, 0, 0);
        acc[c] = __builtin_amdgcn_mfma_f32_16x16x32_bf16(al[2], b2, acc[c], 0, 0, 0);
        acc[c] = __builtin_amdgcn_mfma_f32_16x16x32_bf16(al[3], b3, acc[c], 0, 0, 0);
    }
    __syncthreads();  // Wh reads done
    // phase-2 stage: WT <- bf16_lo(W)
    for (int idx = t; idx < 128 * 128; idx += 256) {
        int f = idx >> 7, j = idx & 127;
        float v = ldf(W, idx, f32);
        unsigned short h = f2bf(v);
        WT[j * 136 + f] = f2bf(v - bf2f(h));
    }
    __syncthreads();
    // phase-2 compute: xh@Wl
#pragma unroll
    for (int c = 0; c < 8; c++) {
        const short8* bp = (const short8*)(&WT[(c * 16 + col) * 136 + quad * 8]);
        acc[c] = __builtin_amdgcn_mfma_f32_16x16x32_bf16(ah[0], bp[0], acc[c], 0, 0, 0);
        acc[c] = __builtin_amdgcn_mfma_f32_16x16x32_bf16(ah[1], bp[4], acc[c], 0, 0, 0);
        acc[c] = __builtin_amdgcn_mfma_f32_16x16x32_bf16(ah[2], bp[8], acc[c], 0, 0, 0);
        acc[c] = __builtin_amdgcn_mfma_f32_16x16x32_bf16(ah[3], bp[12], acc[c], 0, 0, 0);
    }
    // epilogue A: projb store; C layout: col=lane&15, row=quad*4+reg (HW-validated)
#pragma unroll
    for (int r = 0; r < 4; r++) {
        int row = row0 + quad * 4 + r;
        if (row < N) {
#pragma unroll
            for (int c = 0; c < 8; c++)
                projb[(size_t)row * 128 + c * 16 + col] = f2bf(acc[c][r]);
        }
    }
    // epilogue B: fused scores s[n][h] = sum_j proj[n][j]*a[j], h = j>>5
    float asv[8], atv[8];
#pragma unroll
    for (int c = 0; c < 8; c++) {
        int j = c * 16 + col;
        asv[c] = ldf(a_src, j, f32);
        atv[c] = ldf(a_trg, j, f32);
    }
#pragma unroll
    for (int r = 0; r < 4; r++) {
        int row = row0 + quad * 4 + r;
        float ps[4] = {0.f, 0.f, 0.f, 0.f}, pt[4] = {0.f, 0.f, 0.f, 0.f};
#pragma unroll
        for (int c = 0; c < 8; c++) {
            int h = c >> 1;
            ps[h] += acc[c][r] * asv[c];
            pt[h] += acc[c][r] * atv[c];
        }
#pragma unroll
        for (int k = 1; k < 16; k <<= 1) {
#pragma unroll
            for (int h = 0; h < 4; h++) {
                ps[h] += __shfl_xor(ps[h], k, 16);
                pt[h] += __shfl_xor(pt[h], k, 16);
            }
        }
        if (col == 0 && row < N) {
#pragma unroll
            for (int h = 0; h < 4; h++) {
                ssrc[(size_t)row * 4 + h] = ps[h];
                strg[(size_t)row * 4 + h] = pt[h];
            }
        }
    }
}

__device__ inline void edge_scores(const float* ssrc, const float* strg,
                                   int src, int trg, float* v) {
    float4 a = *(const float4*)(ssrc + (size_t)src * 4);
    float4 b = *(const float4*)(strg + (size_t)trg * 4);
    v[0] = a.x + b.x; v[1] = a.y + b.y; v[2] = a.z + b.z; v[3] = a.w + b.w;
#pragma unroll
    for (int h = 0; h < 4; h++) v[h] = v[h] > 0.f ? v[h] : 0.2f * v[h];
}

// ---- KE: in-degree histogram + per-block max (no same-address atomics) ----
__global__ __launch_bounds__(256) void kE_count_max(
    const int* __restrict__ ei, const float* __restrict__ ssrc,
    const float* __restrict__ strg, const int* __restrict__ flags,
    int* __restrict__ counts, float* __restrict__ blockmax, int E, int N)
{
    int e64 = flags[1];
    int e = blockIdx.x * 256 + threadIdx.x;
    float m = -3.0e38f;
    if (e < E) {
        int src = min(max(lde(ei, e, e64), 0), N - 1);
        int trg = min(max(lde(ei, E + e, e64), 0), N - 1);
        atomicAdd(&counts[trg], 1);
        float v[4];
        edge_scores(ssrc, strg, src, trg, v);
        m = fmaxf(fmaxf(v[0], v[1]), fmaxf(v[2], v[3]));
    }
#pragma unroll
    for (int k = 1; k < 64; k <<= 1) m = fmaxf(m, __shfl_xor(m, k, 64));
    __shared__ float wm[4];
    if ((threadIdx.x & 63) == 0) wm[threadIdx.x >> 6] = m;
    __syncthreads();
    if (threadIdx.x == 0)
        blockmax[blockIdx.x] = fmaxf(fmaxf(wm[0], wm[1]), fmaxf(wm[2], wm[3]));
}

// ---- S1: per-block sums of counts (coalesced) ----
__global__ __launch_bounds__(256) void kS1_psum(
    const int* __restrict__ counts, int* __restrict__ partials, int NP1)
{
    int idx = blockIdx.x * 256 + threadIdx.x;
    int v = (idx < NP1) ? counts[idx] : 0;
#pragma unroll
    for (int k = 1; k < 64; k <<= 1) v += __shfl_xor(v, k, 64);
    __shared__ int wsum[4];
    if ((threadIdx.x & 63) == 0) wsum[threadIdx.x >> 6] = v;
    __syncthreads();
    if (threadIdx.x == 0)
        partials[blockIdx.x] = wsum[0] + wsum[1] + wsum[2] + wsum[3];
}

// ---- S2: exclusive scan of partials (<=256) + Mval reduction (1 block) ----
__global__ __launch_bounds__(256) void kS2_scanp(
    int* __restrict__ partials, int nb,
    const float* __restrict__ blockmax, float* __restrict__ Mval, int nbm)
{
    int t = threadIdx.x;
    if (nb <= 256) {
        __shared__ int lds[256];
        int v = (t < nb) ? partials[t] : 0;
        lds[t] = v;
        __syncthreads();
        int incl = v;
        for (int st = 1; st < 256; st <<= 1) {
            int add = (t >= st) ? lds[t - st] : 0;
            __syncthreads();
            incl += add;
            lds[t] = incl;
            __syncthreads();
        }
        if (t < nb) partials[t] = incl - v;
    } else if (t == 0) {
        int run = 0;
        for (int i = 0; i < nb; i++) { int c = partials[i]; partials[i] = run; run += c; }
    }
    __syncthreads();
    float m = -3.0e38f;
    for (int i = t; i < nbm; i += 256) m = fmaxf(m, blockmax[i]);
#pragma unroll
    for (int k = 1; k < 64; k <<= 1) m = fmaxf(m, __shfl_xor(m, k, 64));
    __shared__ float wm[4];
    if ((t & 63) == 0) wm[t >> 6] = m;
    __syncthreads();
    if (t == 0) *Mval = fmaxf(fmaxf(wm[0], wm[1]), fmaxf(wm[2], wm[3]));
}

// ---- S3: per-block exclusive scan + base -> offsets (coalesced) ----
__global__ __launch_bounds__(256) void kS3_offs(
    const int* __restrict__ counts, const int* __restrict__ partials,
    int* __restrict__ offsets, int NP1)
{
    int t = threadIdx.x;
    int idx = blockIdx.x * 256 + t;
    int v = (idx < NP1) ? counts[idx] : 0;
    __shared__ int lds[256];
    lds[t] = v;
    __syncthreads();
    int incl = v;
    for (int st = 1; st < 256; st <<= 1) {
        int add = (t >= st) ? lds[t - st] : 0;
        __syncthreads();
        incl += add;
        lds[t] = incl;
        __syncthreads();
    }
    if (idx < NP1) offsets[idx] = partials[blockIdx.x] + incl - v;
}

// ---- K2c (eexp variant): CSR scatter + per-edge exp(leaky(score)-M) ----
__global__ __launch_bounds__(256) void k2c_scatter_exp(
    const int* __restrict__ ei, const int* __restrict__ offsets,
    const float* __restrict__ ssrc, const float* __restrict__ strg,
    const int* __restrict__ flags, const float* __restrict__ Mval,
    int* __restrict__ cursor, int* __restrict__ esrc, float4* __restrict__ eexp,
    int E, int N)
{
    int e64 = flags[1];
    int e = blockIdx.x * 256 + threadIdx.x;
    if (e >= E) return;
    float M = *Mval;
    int src = min(max(lde(ei, e, e64), 0), N - 1);
    int trg = min(max(lde(ei, E + e, e64), 0), N - 1);
    int pos = offsets[trg] + atomicAdd(&cursor[trg], 1);
    if (pos < 0 || pos >= E) return;
    esrc[pos] = src;
    float v[4];
    edge_scores(ssrc, strg, src, trg, v);
    eexp[pos] = make_float4(__expf(v[0] - M), __expf(v[1] - M),
                            __expf(v[2] - M), __expf(v[3] - M));
}

// ---- K2c (fallback, no eexp) ----
__global__ __launch_bounds__(256) void k2c_scatter(
    const int* __restrict__ ei, const int* __restrict__ offsets,
    const int* __restrict__ flags, int* __restrict__ cursor,
    int* __restrict__ esrc, int E, int N)
{
    int e64 = flags[1];
    int e = blockIdx.x * 256 + threadIdx.x;
    if (e >= E) return;
    int src = min(max(lde(ei, e, e64), 0), N - 1);
    int trg = min(max(lde(ei, E + e, e64), 0), N - 1);
    int pos = offsets[trg] + atomicAdd(&cursor[trg], 1);
    if (pos >= 0 && pos < E) esrc[pos] = src;
}

// ---- K3 (eexp variant): coalesced eexp reads; no score gathers ----
__global__ __launch_bounds__(256) void k3_agg_e(
    const int* __restrict__ offsets, const int* __restrict__ esrc,
    const float4* __restrict__ eexp, const unsigned short* __restrict__ projb,
    const void* __restrict__ x, const void* __restrict__ bias,
    const int* __restrict__ flags, float* __restrict__ out, int N, int E)
{
    int w = threadIdx.x >> 6;
    int lane = threadIdx.x & 63;
    int n = blockIdx.x * 4 + w;
    int f32 = flags[0];
    bool valid = (n < N);
    int nc = valid ? n : N - 1;
    int off = offsets[nc];
    int d = offsets[nc + 1] - off;
    d = max(0, min(d, E));
    if (!valid) d = 0;

    float den[4] = {0.f, 0.f, 0.f, 0.f};
    for (int i = lane; i < d; i += 64) {
        float4 ev = eexp[off + i];
        den[0] += ev.x; den[1] += ev.y; den[2] += ev.z; den[3] += ev.w;
    }
#pragma unroll
    for (int k = 1; k < 64; k <<= 1)
#pragma unroll
        for (int h = 0; h < 4; h++) den[h] += __shfl_xor(den[h], k, 64);
    float inv[4];
#pragma unroll
    for (int h = 0; h < 4; h++) inv[h] = 1.0f / (den[h] + 1e-16f);

    __shared__ int dmax_s[4];
    if (lane == 0) dmax_s[w] = d;
    __syncthreads();
    int dmx = max(max(dmax_s[0], dmax_s[1]), max(dmax_s[2], dmax_s[3]));

    __shared__ int lsrc[4][64];
    __shared__ float latt[4][64 * 5];
    float acc0 = 0.f, acc1 = 0.f;
    int h01 = lane >> 4;
    for (int base = 0; base < dmx; base += 64) {
        int cd = min(64, d - base);
        if (lane < cd) {
            int s = min(max(esrc[off + base + lane], 0), N - 1);
            lsrc[w][lane] = s;
            float4 ev = eexp[off + base + lane];
            latt[w][lane * 5 + 0] = ev.x * inv[0];
            latt[w][lane * 5 + 1] = ev.y * inv[1];
            latt[w][lane * 5 + 2] = ev.z * inv[2];
            latt[w][lane * 5 + 3] = ev.w * inv[3];
        }
        __syncthreads();
        for (int k = 0; k < cd; k++) {
            int s = lsrc[w][k];
            float att = latt[w][k * 5 + h01];
            unsigned p = *(const unsigned*)(projb + (size_t)s * 128 + lane * 2);
            acc0 = fmaf(bf2f((unsigned short)(p & 0xffffu)), att, acc0);
            acc1 = fmaf(bf2f((unsigned short)(p >> 16)), att, acc1);
        }
        __syncthreads();
    }

    if (!valid) return;
    int j0 = lane * 2;
    float o0 = acc0 + ldf(x, n * 128 + j0, f32) + ldf(bias, j0, f32);
    float o1 = acc1 + ldf(x, n * 128 + j0 + 1, f32) + ldf(bias, j0 + 1, f32);
    o0 = o0 > 0.f ? o0 : __expf(o0) - 1.f;
    o1 = o1 > 0.f ? o1 : __expf(o1) - 1.f;
    out[(size_t)n * 128 + j0]     = o0;
    out[(size_t)n * 128 + j0 + 1] = o1;
}

// ---- K3 (fallback, gathers scores) ----
__global__ __launch_bounds__(256) void k3_agg_g(
    const int* __restrict__ offsets, const int* __restrict__ esrc,
    const float* __restrict__ ssrc, const float* __restrict__ strg,
    const unsigned short* __restrict__ projb, const void* __restrict__ x,
    const void* __restrict__ bias, const int* __restrict__ flags,
    const float* __restrict__ Mval, float* __restrict__ out, int N, int E)
{
    int w = threadIdx.x >> 6;
    int lane = threadIdx.x & 63;
    int n = blockIdx.x * 4 + w;
    int f32 = flags[0];
    bool valid = (n < N);
    int nc = valid ? n : N - 1;
    int off = offsets[nc];
    int d = offsets[nc + 1] - off;
    d = max(0, min(d, E));
    if (!valid) d = 0;
    float M = *Mval;
    float4 stv = *(const float4*)(strg + (size_t)nc * 4);
    float st[4] = {stv.x, stv.y, stv.z, stv.w};
    float den[4] = {0.f, 0.f, 0.f, 0.f};
    for (int i = lane; i < d; i += 64) {
        int s = min(max(esrc[off + i], 0), N - 1);
        float4 ssv = *(const float4*)(ssrc + (size_t)s * 4);
        float sv[4] = {ssv.x, ssv.y, ssv.z, ssv.w};
#pragma unroll
        for (int h = 0; h < 4; h++) {
            float v = sv[h] + st[h];
            v = v > 0.f ? v : 0.2f * v;
            den[h] += __expf(v - M);
        }
    }
#pragma unroll
    for (int k = 1; k < 64; k <<= 1)
#pragma unroll
        for (int h = 0; h < 4; h++) den[h] += __shfl_xor(den[h], k, 64);
    float inv[4];
#pragma unroll
    for (int h = 0; h < 4; h++) inv[h] = 1.0f / (den[h] + 1e-16f);
    __shared__ int dmax_s[4];
    if (lane == 0) dmax_s[w] = d;
    __syncthreads();
    int dmx = max(max(dmax_s[0], dmax_s[1]), max(dmax_s[2], dmax_s[3]));
    __shared__ int lsrc[4][64];
    __shared__ float latt[4][64 * 5];
    float acc0 = 0.f, acc1 = 0.f;
    int h01 = lane >> 4;
    for (int base = 0; base < dmx; base += 64) {
        int cd = min(64, d - base);
        if (lane < cd) {
            int s = min(max(esrc[off + base + lane], 0), N - 1);
            lsrc[w][lane] = s;
            float4 ssv = *(const float4*)(ssrc + (size_t)s * 4);
            float sv[4] = {ssv.x, ssv.y, ssv.z, ssv.w};
#pragma unroll
            for (int h = 0; h < 4; h++) {
                float v = sv[h] + st[h];
                v = v > 0.f ? v : 0.2f * v;
                latt[w][lane * 5 + h] = __expf(v - M) * inv[h];
            }
        }
        __syncthreads();
        for (int k = 0; k < cd; k++) {
            int s = lsrc[w][k];
            float att = latt[w][k * 5 + h01];
            unsigned p = *(const unsigned*)(projb + (size_t)s * 128 + lane * 2);
            acc0 = fmaf(bf2f((unsigned short)(p & 0xffffu)), att, acc0);
            acc1 = fmaf(bf2f((unsigned short)(p >> 16)), att, acc1);
        }
        __syncthreads();
    }
    if (!valid) return;
    int j0 = lane * 2;
    float o0 = acc0 + ldf(x, n * 128 + j0, f32) + ldf(bias, j0, f32);
    float o1 = acc1 + ldf(x, n * 128 + j0 + 1, f32) + ldf(bias, j0 + 1, f32);
    o0 = o0 > 0.f ? o0 : __expf(o0) - 1.f;
    o1 = o1 > 0.f ? o1 : __expf(o1) - 1.f;
    out[(size_t)n * 128 + j0]     = o0;
    out[(size_t)n * 128 + j0 + 1] = o1;
}

extern "C" void kernel_launch(void* const* d_in, const int* in_sizes, int n_in,
                              void* d_out, int out_size, void* d_ws, size_t ws_size,
                              hipStream_t stream)
{
    const void* x     = d_in[0];
    const int*  ei    = (const int*)d_in[1];
    const void* W     = d_in[2];
    const void* a_src = d_in[3];
    const void* a_trg = d_in[4];
    const void* bias  = d_in[5];
    float* out = (float*)d_out;
    int N = in_sizes[0] / 128;
    int E = N * 16;
    if (in_sizes[1] / 2 < E) E = in_sizes[1] / 2;
    int nbE = (E + 255) / 256;
    int NP1 = N + 1;
    int nbS = (NP1 + 255) / 256;

    char* ws = (char*)d_ws;
    size_t o = 0;
    auto alloc = [&](size_t bytes) {
        size_t r = o;
        o = (o + bytes + 255) & ~(size_t)255;
        return r;
    };
    int* flags = (int*)(ws + alloc(256));
    unsigned short* projb = (unsigned short*)(ws + alloc((size_t)N * 128 * 2));
    float* ssrc  = (float*)(ws + alloc((size_t)N * 4 * 4));
    float* strg  = (float*)(ws + alloc((size_t)N * 4 * 4));
    float* Mval  = (float*)(ws + alloc(256));
    int* counts  = (int*)(ws + alloc((size_t)NP1 * 4));
    int* offsets = (int*)(ws + alloc((size_t)NP1 * 4));
    int* cursor  = (int*)(ws + alloc((size_t)N * 4));
    int* esrc    = (int*)(ws + alloc((size_t)E * 4));
    float* blockmax = (float*)(ws + alloc((size_t)nbE * 4));
    int* partials = (int*)(ws + alloc((size_t)nbS * 4));
    size_t base = o;
    size_t need_eexp = base + (size_t)E * 16 + 256;

    k_det<<<1, 256, 0, stream>>>(x, ei, flags);
    k0_init<<<(N + 256) / 256, 256, 0, stream>>>(counts, cursor, N);
    k1_gemm<<<(N + 63) / 64, 256, 0, stream>>>(x, W, a_src, a_trg, flags, projb, ssrc, strg, N);
    kE_count_max<<<nbE, 256, 0, stream>>>(ei, ssrc, strg, flags, counts, blockmax, E, N);
    kS1_psum<<<nbS, 256, 0, stream>>>(counts, partials, NP1);
    kS2_scanp<<<1, 256, 0, stream>>>(partials, nbS, blockmax, Mval, nbE);
    kS3_offs<<<nbS, 256, 0, stream>>>(counts, partials, offsets, NP1);

    if (ws_size >= need_eexp) {
        float4* eexp = (float4*)(ws + alloc((size_t)E * 16));
        k2c_scatter_exp<<<nbE, 256, 0, stream>>>(ei, offsets, ssrc, strg, flags, Mval,
                                                 cursor, esrc, eexp, E, N);
        k3_agg_e<<<(N + 3) / 4, 256, 0, stream>>>(offsets, esrc, eexp, projb, x, bias,
                                                  flags, out, N, E);
    } else {
        k2c_scatter<<<nbE, 256, 0, stream>>>(ei, offsets, flags, cursor, esrc, E, N);
        k3_agg_g<<<(N + 3) / 4, 256, 0, stream>>>(offsets, esrc, ssrc, strg, projb, x, bias,
                                                  flags, Mval, out, N, E);
    }
}

// Round 10
// 268.223 us; speedup vs baseline: 3.2097x; 1.1078x over previous
//
#include <hip/hip_runtime.h>
#include <stdint.h>

typedef __attribute__((ext_vector_type(8))) short short8;
typedef __attribute__((ext_vector_type(4))) float floatx4;

__device__ inline float bf2f(unsigned short b) {
    unsigned u = ((unsigned)b) << 16;
    return __builtin_bit_cast(float, u);
}
__device__ inline unsigned short f2bf(float f) {
    unsigned u = __builtin_bit_cast(unsigned, f);
    unsigned r = (u + 0x7fffu + ((u >> 16) & 1u)) >> 16;
    return (unsigned short)r;
}
__device__ inline float ldf(const void* p, int i, int f32) {
    return f32 ? ((const float*)p)[i] : bf2f(((const unsigned short*)p)[i]);
}
__device__ inline int lde(const int* ei, int idx, int is64) {
    return is64 ? ei[2 * idx] : ei[idx];
}

// ---- K_det: input dtype layouts (deterministic, every launch) ----
__global__ void k_det(const void* x, const int* ei, int* flags) {
    __shared__ int h1, h2;
    if (threadIdx.x == 0) { h1 = 0; h2 = 0; }
    __syncthreads();
    const unsigned short* xs = (const unsigned short*)x;
    int c1 = 0;
    for (int i = threadIdx.x * 2; i < 65536; i += 512)
        if ((xs[i] & 0x7f80u) == 0x7f80u) c1++;   // fp32 mantissa halves ~1/256; bf16 never
    int c2 = 0;
    for (int i = threadIdx.x * 2 + 1; i < 8192; i += 512)
        if (ei[i] != 0) c2++;                      // int64 high words are 0
    atomicAdd(&h1, c1);
    atomicAdd(&h2, c2);
    __syncthreads();
    if (threadIdx.x == 0) { flags[0] = (h1 >= 8); flags[1] = (h2 < 8); }
}

// ---- K0: zero counts/cursor ----
__global__ void k0_init(int* counts, int* cursor, int N) {
    int i = blockIdx.x * blockDim.x + threadIdx.x;
    if (i <= N) counts[i] = 0;
    if (i < N) cursor[i] = 0;
}

// ---- K_conv: W -> transposed bf16 hi/lo (once, not per GEMM block) ----
// WhT[n*128+k] = bf16_hi(W[k*128+n]); WlT = residual
__global__ __launch_bounds__(256) void k_conv(
    const void* __restrict__ W, const int* __restrict__ flags,
    unsigned short* __restrict__ WhT, unsigned short* __restrict__ WlT)
{
    int f32 = flags[0];
    int idx = blockIdx.x * 256 + threadIdx.x;   // 64 blocks
    if (idx >= 128 * 128) return;
    int n = idx >> 7, k = idx & 127;
    float v = ldf(W, k * 128 + n, f32);
    unsigned short h = f2bf(v);
    WhT[idx] = h;
    WlT[idx] = f2bf(v - bf2f(h));
}

// ---- K1: proj = x@W via bf16x3 MFMA, vectorized staging + fused scores ----
__global__ __launch_bounds__(256) void k1_gemm(
    const void* __restrict__ x, const unsigned short* __restrict__ WhT,
    const unsigned short* __restrict__ WlT, const void* __restrict__ a_src,
    const void* __restrict__ a_trg, const int* __restrict__ flags,
    unsigned short* __restrict__ projb, float* __restrict__ ssrc,
    float* __restrict__ strg, int N)
{
    __shared__ __align__(16) unsigned short WT[128 * 136];
    int t = threadIdx.x;
    int f32 = flags[0];
    // stage WhT: 2048 16B chunks, coalesced dwordx4 both sides
    for (int i = t; i < 2048; i += 256) {
        int row = i >> 4, ch = (i & 15) * 8;
        *(short8*)&WT[row * 136 + ch] = *(const short8*)&WhT[row * 128 + ch];
    }
    __syncthreads();
    int wave = t >> 6, lane = t & 63;
    int col = lane & 15, quad = lane >> 4;
    int row0 = blockIdx.x * 64 + wave * 16;
    int m = row0 + col;
    if (m >= N) m = N - 1;
    // A frags: A[m=col][k=kb*32+quad*8+j], vectorized per dtype (uniform branch)
    short8 ah[4], al[4];
    if (f32) {
        const float* xf = (const float*)x + (size_t)m * 128 + quad * 8;
#pragma unroll
        for (int kb = 0; kb < 4; kb++) {
            float4 v0 = *(const float4*)(xf + kb * 32);
            float4 v1 = *(const float4*)(xf + kb * 32 + 4);
            float vv[8] = {v0.x, v0.y, v0.z, v0.w, v1.x, v1.y, v1.z, v1.w};
#pragma unroll
            for (int j = 0; j < 8; j++) {
                unsigned short h = f2bf(vv[j]);
                ah[kb][j] = (short)h;
                al[kb][j] = (short)f2bf(vv[j] - bf2f(h));
            }
        }
    } else {
        const unsigned short* xb = (const unsigned short*)x + (size_t)m * 128 + quad * 8;
#pragma unroll
        for (int kb = 0; kb < 4; kb++)
            ah[kb] = *(const short8*)(xb + kb * 32);
    }
    floatx4 acc[8];
#pragma unroll
    for (int c = 0; c < 8; c++) acc[c] = (floatx4){0.f, 0.f, 0.f, 0.f};
    // phase-1: xh@Wh (+ xl@Wh when fp32)
#pragma unroll
    for (int c = 0; c < 8; c++) {
        const short8* bp = (const short8*)(&WT[(c * 16 + col) * 136 + quad * 8]);
        short8 b0 = bp[0], b1 = bp[4], b2 = bp[8], b3 = bp[12];
        acc[c] = __builtin_amdgcn_mfma_f32_16x16x32_bf16(ah[0], b0, acc[c], 0, 0, 0);
        acc[c] = __builtin_amdgcn_mfma_f32_16x16x32_bf16(ah[1], b1, acc[c], 0, 0, 0);
        acc[c] = __builtin_amdgcn_mfma_f32_16x16x32_bf16(ah[2], b2, acc[c], 0, 0, 0);
        acc[c] = __builtin_amdgcn_mfma_f32_16x16x32_bf16(ah[3], b3, acc[c], 0, 0, 0);
        if (f32) {
            acc[c] = __builtin_amdgcn_mfma_f32_16x16x32_bf16(al[0], b0, acc[c], 0, 0, 0);
            acc[c] = __builtin_amdgcn_mfma_f32_16x16x32_bf16(al[1], b1, acc[c], 0, 0, 0);
            acc[c] = __builtin_amdgcn_mfma_f32_16x16x32_bf16(al[2], b2, acc[c], 0, 0, 0);
            acc[c] = __builtin_amdgcn_mfma_f32_16x16x32_bf16(al[3], b3, acc[c], 0, 0, 0);
        }
    }
    if (f32) {  // phase-2: xh@Wl (bf16 inputs have Wl==0 -> skip entirely)
        __syncthreads();
        for (int i = t; i < 2048; i += 256) {
            int row = i >> 4, ch = (i & 15) * 8;
            *(short8*)&WT[row * 136 + ch] = *(const short8*)&WlT[row * 128 + ch];
        }
        __syncthreads();
#pragma unroll
        for (int c = 0; c < 8; c++) {
            const short8* bp = (const short8*)(&WT[(c * 16 + col) * 136 + quad * 8]);
            acc[c] = __builtin_amdgcn_mfma_f32_16x16x32_bf16(ah[0], bp[0], acc[c], 0, 0, 0);
            acc[c] = __builtin_amdgcn_mfma_f32_16x16x32_bf16(ah[1], bp[4], acc[c], 0, 0, 0);
            acc[c] = __builtin_amdgcn_mfma_f32_16x16x32_bf16(ah[2], bp[8], acc[c], 0, 0, 0);
            acc[c] = __builtin_amdgcn_mfma_f32_16x16x32_bf16(ah[3], bp[12], acc[c], 0, 0, 0);
        }
    }
    // epilogue A: projb store; C layout: col=lane&15, row=quad*4+reg (HW-validated)
#pragma unroll
    for (int r = 0; r < 4; r++) {
        int row = row0 + quad * 4 + r;
        if (row < N) {
#pragma unroll
            for (int c = 0; c < 8; c++)
                projb[(size_t)row * 128 + c * 16 + col] = f2bf(acc[c][r]);
        }
    }
    // epilogue B: fused scores s[n][h] = sum_j proj[n][j]*a[j], h = j>>5
    float asv[8], atv[8];
#pragma unroll
    for (int c = 0; c < 8; c++) {
        int j = c * 16 + col;
        asv[c] = ldf(a_src, j, f32);
        atv[c] = ldf(a_trg, j, f32);
    }
#pragma unroll
    for (int r = 0; r < 4; r++) {
        int row = row0 + quad * 4 + r;
        float ps[4] = {0.f, 0.f, 0.f, 0.f}, pt[4] = {0.f, 0.f, 0.f, 0.f};
#pragma unroll
        for (int c = 0; c < 8; c++) {
            int h = c >> 1;
            ps[h] += acc[c][r] * asv[c];
            pt[h] += acc[c][r] * atv[c];
        }
#pragma unroll
        for (int k = 1; k < 16; k <<= 1) {
#pragma unroll
            for (int h = 0; h < 4; h++) {
                ps[h] += __shfl_xor(ps[h], k, 16);
                pt[h] += __shfl_xor(pt[h], k, 16);
            }
        }
        if (col == 0 && row < N) {
#pragma unroll
            for (int h = 0; h < 4; h++) {
                ssrc[(size_t)row * 4 + h] = ps[h];
                strg[(size_t)row * 4 + h] = pt[h];
            }
        }
    }
}

__device__ inline void edge_scores(const float* ssrc, const float* strg,
                                   int src, int trg, float* v) {
    float4 a = *(const float4*)(ssrc + (size_t)src * 4);
    float4 b = *(const float4*)(strg + (size_t)trg * 4);
    v[0] = a.x + b.x; v[1] = a.y + b.y; v[2] = a.z + b.z; v[3] = a.w + b.w;
#pragma unroll
    for (int h = 0; h < 4; h++) v[h] = v[h] > 0.f ? v[h] : 0.2f * v[h];
}

// ---- KE: in-degree histogram + per-block max (no same-address atomics) ----
__global__ __launch_bounds__(256) void kE_count_max(
    const int* __restrict__ ei, const float* __restrict__ ssrc,
    const float* __restrict__ strg, const int* __restrict__ flags,
    int* __restrict__ counts, float* __restrict__ blockmax, int E, int N)
{
    int e64 = flags[1];
    int e = blockIdx.x * 256 + threadIdx.x;
    float m = -3.0e38f;
    if (e < E) {
        int src = min(max(lde(ei, e, e64), 0), N - 1);
        int trg = min(max(lde(ei, E + e, e64), 0), N - 1);
        atomicAdd(&counts[trg], 1);
        float v[4];
        edge_scores(ssrc, strg, src, trg, v);
        m = fmaxf(fmaxf(v[0], v[1]), fmaxf(v[2], v[3]));
    }
#pragma unroll
    for (int k = 1; k < 64; k <<= 1) m = fmaxf(m, __shfl_xor(m, k, 64));
    __shared__ float wm[4];
    if ((threadIdx.x & 63) == 0) wm[threadIdx.x >> 6] = m;
    __syncthreads();
    if (threadIdx.x == 0)
        blockmax[blockIdx.x] = fmaxf(fmaxf(wm[0], wm[1]), fmaxf(wm[2], wm[3]));
}

// ---- S1: per-block sums of counts (coalesced) ----
__global__ __launch_bounds__(256) void kS1_psum(
    const int* __restrict__ counts, int* __restrict__ partials, int NP1)
{
    int idx = blockIdx.x * 256 + threadIdx.x;
    int v = (idx < NP1) ? counts[idx] : 0;
#pragma unroll
    for (int k = 1; k < 64; k <<= 1) v += __shfl_xor(v, k, 64);
    __shared__ int wsum[4];
    if ((threadIdx.x & 63) == 0) wsum[threadIdx.x >> 6] = v;
    __syncthreads();
    if (threadIdx.x == 0)
        partials[blockIdx.x] = wsum[0] + wsum[1] + wsum[2] + wsum[3];
}

// ---- S2: exclusive scan of partials (<=256) + Mval reduction (1 block) ----
__global__ __launch_bounds__(256) void kS2_scanp(
    int* __restrict__ partials, int nb,
    const float* __restrict__ blockmax, float* __restrict__ Mval, int nbm)
{
    int t = threadIdx.x;
    if (nb <= 256) {
        __shared__ int lds[256];
        int v = (t < nb) ? partials[t] : 0;
        lds[t] = v;
        __syncthreads();
        int incl = v;
        for (int st = 1; st < 256; st <<= 1) {
            int add = (t >= st) ? lds[t - st] : 0;
            __syncthreads();
            incl += add;
            lds[t] = incl;
            __syncthreads();
        }
        if (t < nb) partials[t] = incl - v;
    } else if (t == 0) {
        int run = 0;
        for (int i = 0; i < nb; i++) { int c = partials[i]; partials[i] = run; run += c; }
    }
    __syncthreads();
    float m = -3.0e38f;
    for (int i = t; i < nbm; i += 256) m = fmaxf(m, blockmax[i]);
#pragma unroll
    for (int k = 1; k < 64; k <<= 1) m = fmaxf(m, __shfl_xor(m, k, 64));
    __shared__ float wm[4];
    if ((t & 63) == 0) wm[t >> 6] = m;
    __syncthreads();
    if (t == 0) *Mval = fmaxf(fmaxf(wm[0], wm[1]), fmaxf(wm[2], wm[3]));
}

// ---- S3: per-block exclusive scan + base -> offsets (coalesced) ----
__global__ __launch_bounds__(256) void kS3_offs(
    const int* __restrict__ counts, const int* __restrict__ partials,
    int* __restrict__ offsets, int NP1)
{
    int t = threadIdx.x;
    int idx = blockIdx.x * 256 + t;
    int v = (idx < NP1) ? counts[idx] : 0;
    __shared__ int lds[256];
    lds[t] = v;
    __syncthreads();
    int incl = v;
    for (int st = 1; st < 256; st <<= 1) {
        int add = (t >= st) ? lds[t - st] : 0;
        __syncthreads();
        incl += add;
        lds[t] = incl;
        __syncthreads();
    }
    if (idx < NP1) offsets[idx] = partials[blockIdx.x] + incl - v;
}

// ---- K2c (eexp variant): CSR scatter + per-edge exp(leaky(score)-M) ----
__global__ __launch_bounds__(256) void k2c_scatter_exp(
    const int* __restrict__ ei, const int* __restrict__ offsets,
    const float* __restrict__ ssrc, const float* __restrict__ strg,
    const int* __restrict__ flags, const float* __restrict__ Mval,
    int* __restrict__ cursor, int* __restrict__ esrc, float4* __restrict__ eexp,
    int E, int N)
{
    int e64 = flags[1];
    int e = blockIdx.x * 256 + threadIdx.x;
    if (e >= E) return;
    float M = *Mval;
    int src = min(max(lde(ei, e, e64), 0), N - 1);
    int trg = min(max(lde(ei, E + e, e64), 0), N - 1);
    int pos = offsets[trg] + atomicAdd(&cursor[trg], 1);
    if (pos < 0 || pos >= E) return;
    esrc[pos] = src;
    float v[4];
    edge_scores(ssrc, strg, src, trg, v);
    eexp[pos] = make_float4(__expf(v[0] - M), __expf(v[1] - M),
                            __expf(v[2] - M), __expf(v[3] - M));
}

// ---- K2c (fallback, no eexp) ----
__global__ __launch_bounds__(256) void k2c_scatter(
    const int* __restrict__ ei, const int* __restrict__ offsets,
    const int* __restrict__ flags, int* __restrict__ cursor,
    int* __restrict__ esrc, int E, int N)
{
    int e64 = flags[1];
    int e = blockIdx.x * 256 + threadIdx.x;
    if (e >= E) return;
    int src = min(max(lde(ei, e, e64), 0), N - 1);
    int trg = min(max(lde(ei, E + e, e64), 0), N - 1);
    int pos = offsets[trg] + atomicAdd(&cursor[trg], 1);
    if (pos >= 0 && pos < E) esrc[pos] = src;
}

// ---- K3 (eexp variant): coalesced eexp reads; no score gathers ----
__global__ __launch_bounds__(256) void k3_agg_e(
    const int* __restrict__ offsets, const int* __restrict__ esrc,
    const float4* __restrict__ eexp, const unsigned short* __restrict__ projb,
    const void* __restrict__ x, const void* __restrict__ bias,
    const int* __restrict__ flags, float* __restrict__ out, int N, int E)
{
    int w = threadIdx.x >> 6;
    int lane = threadIdx.x & 63;
    int n = blockIdx.x * 4 + w;
    int f32 = flags[0];
    bool valid = (n < N);
    int nc = valid ? n : N - 1;
    int off = offsets[nc];
    int d = offsets[nc + 1] - off;
    d = max(0, min(d, E));
    if (!valid) d = 0;

    float den[4] = {0.f, 0.f, 0.f, 0.f};
    for (int i = lane; i < d; i += 64) {
        float4 ev = eexp[off + i];
        den[0] += ev.x; den[1] += ev.y; den[2] += ev.z; den[3] += ev.w;
    }
#pragma unroll
    for (int k = 1; k < 64; k <<= 1)
#pragma unroll
        for (int h = 0; h < 4; h++) den[h] += __shfl_xor(den[h], k, 64);
    float inv[4];
#pragma unroll
    for (int h = 0; h < 4; h++) inv[h] = 1.0f / (den[h] + 1e-16f);

    __shared__ int dmax_s[4];
    if (lane == 0) dmax_s[w] = d;
    __syncthreads();
    int dmx = max(max(dmax_s[0], dmax_s[1]), max(dmax_s[2], dmax_s[3]));

    __shared__ int lsrc[4][64];
    __shared__ float latt[4][64 * 5];
    float acc0 = 0.f, acc1 = 0.f;
    int h01 = lane >> 4;
    for (int base = 0; base < dmx; base += 64) {
        int cd = min(64, d - base);
        if (lane < cd) {
            int s = min(max(esrc[off + base + lane], 0), N - 1);
            lsrc[w][lane] = s;
            float4 ev = eexp[off + base + lane];
            latt[w][lane * 5 + 0] = ev.x * inv[0];
            latt[w][lane * 5 + 1] = ev.y * inv[1];
            latt[w][lane * 5 + 2] = ev.z * inv[2];
            latt[w][lane * 5 + 3] = ev.w * inv[3];
        }
        __syncthreads();
        for (int k = 0; k < cd; k++) {
            int s = lsrc[w][k];
            float att = latt[w][k * 5 + h01];
            unsigned p = *(const unsigned*)(projb + (size_t)s * 128 + lane * 2);
            acc0 = fmaf(bf2f((unsigned short)(p & 0xffffu)), att, acc0);
            acc1 = fmaf(bf2f((unsigned short)(p >> 16)), att, acc1);
        }
        __syncthreads();
    }

    if (!valid) return;
    int j0 = lane * 2;
    float o0 = acc0 + ldf(x, n * 128 + j0, f32) + ldf(bias, j0, f32);
    float o1 = acc1 + ldf(x, n * 128 + j0 + 1, f32) + ldf(bias, j0 + 1, f32);
    o0 = o0 > 0.f ? o0 : __expf(o0) - 1.f;
    o1 = o1 > 0.f ? o1 : __expf(o1) - 1.f;
    out[(size_t)n * 128 + j0]     = o0;
    out[(size_t)n * 128 + j0 + 1] = o1;
}

// ---- K3 (fallback, gathers scores) ----
__global__ __launch_bounds__(256) void k3_agg_g(
    const int* __restrict__ offsets, const int* __restrict__ esrc,
    const float* __restrict__ ssrc, const float* __restrict__ strg,
    const unsigned short* __restrict__ projb, const void* __restrict__ x,
    const void* __restrict__ bias, const int* __restrict__ flags,
    const float* __restrict__ Mval, float* __restrict__ out, int N, int E)
{
    int w = threadIdx.x >> 6;
    int lane = threadIdx.x & 63;
    int n = blockIdx.x * 4 + w;
    int f32 = flags[0];
    bool valid = (n < N);
    int nc = valid ? n : N - 1;
    int off = offsets[nc];
    int d = offsets[nc + 1] - off;
    d = max(0, min(d, E));
    if (!valid) d = 0;
    float M = *Mval;
    float4 stv = *(const float4*)(strg + (size_t)nc * 4);
    float st[4] = {stv.x, stv.y, stv.z, stv.w};
    float den[4] = {0.f, 0.f, 0.f, 0.f};
    for (int i = lane; i < d; i += 64) {
        int s = min(max(esrc[off + i], 0), N - 1);
        float4 ssv = *(const float4*)(ssrc + (size_t)s * 4);
        float sv[4] = {ssv.x, ssv.y, ssv.z, ssv.w};
#pragma unroll
        for (int h = 0; h < 4; h++) {
            float v = sv[h] + st[h];
            v = v > 0.f ? v : 0.2f * v;
            den[h] += __expf(v - M);
        }
    }
#pragma unroll
    for (int k = 1; k < 64; k <<= 1)
#pragma unroll
        for (int h = 0; h < 4; h++) den[h] += __shfl_xor(den[h], k, 64);
    float inv[4];
#pragma unroll
    for (int h = 0; h < 4; h++) inv[h] = 1.0f / (den[h] + 1e-16f);
    __shared__ int dmax_s[4];
    if (lane == 0) dmax_s[w] = d;
    __syncthreads();
    int dmx = max(max(dmax_s[0], dmax_s[1]), max(dmax_s[2], dmax_s[3]));
    __shared__ int lsrc[4][64];
    __shared__ float latt[4][64 * 5];
    float acc0 = 0.f, acc1 = 0.f;
    int h01 = lane >> 4;
    for (int base = 0; base < dmx; base += 64) {
        int cd = min(64, d - base);
        if (lane < cd) {
            int s = min(max(esrc[off + base + lane], 0), N - 1);
            lsrc[w][lane] = s;
            float4 ssv = *(const float4*)(ssrc + (size_t)s * 4);
            float sv[4] = {ssv.x, ssv.y, ssv.z, ssv.w};
#pragma unroll
            for (int h = 0; h < 4; h++) {
                float v = sv[h] + st[h];
                v = v > 0.f ? v : 0.2f * v;
                latt[w][lane * 5 + h] = __expf(v - M) * inv[h];
            }
        }
        __syncthreads();
        for (int k = 0; k < cd; k++) {
            int s = lsrc[w][k];
            float att = latt[w][k * 5 + h01];
            unsigned p = *(const unsigned*)(projb + (size_t)s * 128 + lane * 2);
            acc0 = fmaf(bf2f((unsigned short)(p & 0xffffu)), att, acc0);
            acc1 = fmaf(bf2f((unsigned short)(p >> 16)), att, acc1);
        }
        __syncthreads();
    }
    if (!valid) return;
    int j0 = lane * 2;
    float o0 = acc0 + ldf(x, n * 128 + j0, f32) + ldf(bias, j0, f32);
    float o1 = acc1 + ldf(x, n * 128 + j0 + 1, f32) + ldf(bias, j0 + 1, f32);
    o0 = o0 > 0.f ? o0 : __expf(o0) - 1.f;
    o1 = o1 > 0.f ? o1 : __expf(o1) - 1.f;
    out[(size_t)n * 128 + j0]     = o0;
    out[(size_t)n * 128 + j0 + 1] = o1;
}

extern "C" void kernel_launch(void* const* d_in, const int* in_sizes, int n_in,
                              void* d_out, int out_size, void* d_ws, size_t ws_size,
                              hipStream_t stream)
{
    const void* x     = d_in[0];
    const int*  ei    = (const int*)d_in[1];
    const void* W     = d_in[2];
    const void* a_src = d_in[3];
    const void* a_trg = d_in[4];
    const void* bias  = d_in[5];
    float* out = (float*)d_out;
    int N = in_sizes[0] / 128;
    int E = N * 16;
    if (in_sizes[1] / 2 < E) E = in_sizes[1] / 2;
    int nbE = (E + 255) / 256;
    int NP1 = N + 1;
    int nbS = (NP1 + 255) / 256;

    char* ws = (char*)d_ws;
    size_t o = 0;
    auto alloc = [&](size_t bytes) {
        size_t r = o;
        o = (o + bytes + 255) & ~(size_t)255;
        return r;
    };
    int* flags = (int*)(ws + alloc(256));
    unsigned short* projb = (unsigned short*)(ws + alloc((size_t)N * 128 * 2));
    float* ssrc  = (float*)(ws + alloc((size_t)N * 4 * 4));
    float* strg  = (float*)(ws + alloc((size_t)N * 4 * 4));
    float* Mval  = (float*)(ws + alloc(256));
    int* counts  = (int*)(ws + alloc((size_t)NP1 * 4));
    int* offsets = (int*)(ws + alloc((size_t)NP1 * 4));
    int* cursor  = (int*)(ws + alloc((size_t)N * 4));
    int* esrc    = (int*)(ws + alloc((size_t)E * 4));
    float* blockmax = (float*)(ws + alloc((size_t)nbE * 4));
    int* partials = (int*)(ws + alloc((size_t)nbS * 4));
    unsigned short* WhT = (unsigned short*)(ws + alloc(128 * 128 * 2));
    unsigned short* WlT = (unsigned short*)(ws + alloc(128 * 128 * 2));
    size_t base = o;
    size_t need_eexp = base + (size_t)E * 16 + 256;

    k_det<<<1, 256, 0, stream>>>(x, ei, flags);
    k0_init<<<(N + 256) / 256, 256, 0, stream>>>(counts, cursor, N);
    k_conv<<<64, 256, 0, stream>>>(W, flags, WhT, WlT);
    k1_gemm<<<(N + 63) / 64, 256, 0, stream>>>(x, WhT, WlT, a_src, a_trg, flags,
                                               projb, ssrc, strg, N);
    kE_count_max<<<nbE, 256, 0, stream>>>(ei, ssrc, strg, flags, counts, blockmax, E, N);
    kS1_psum<<<nbS, 256, 0, stream>>>(counts, partials, NP1);
    kS2_scanp<<<1, 256, 0, stream>>>(partials, nbS, blockmax, Mval, nbE);
    kS3_offs<<<nbS, 256, 0, stream>>>(counts, partials, offsets, NP1);

    if (ws_size >= need_eexp) {
        float4* eexp = (float4*)(ws + alloc((size_t)E * 16));
        k2c_scatter_exp<<<nbE, 256, 0, stream>>>(ei, offsets, ssrc, strg, flags, Mval,
                                                 cursor, esrc, eexp, E, N);
        k3_agg_e<<<(N + 3) / 4, 256, 0, stream>>>(offsets, esrc, eexp, projb, x, bias,
                                                  flags, out, N, E);
    } else {
        k2c_scatter<<<nbE, 256, 0, stream>>>(ei, offsets, flags, cursor, esrc, E, N);
        k3_agg_g<<<(N + 3) / 4, 256, 0, stream>>>(offsets, esrc, ssrc, strg, projb, x, bias,
                                                  flags, Mval, out, N, E);
    }
}

// Round 11
// 267.042 us; speedup vs baseline: 3.2239x; 1.0044x over previous
//
#include <hip/hip_runtime.h>
#include <stdint.h>

typedef __attribute__((ext_vector_type(8))) short short8;
typedef __attribute__((ext_vector_type(4))) float floatx4;

__device__ inline float bf2f(unsigned short b) {
    unsigned u = ((unsigned)b) << 16;
    return __builtin_bit_cast(float, u);
}
__device__ inline unsigned short f2bf(float f) {
    unsigned u = __builtin_bit_cast(unsigned, f);
    unsigned r = (u + 0x7fffu + ((u >> 16) & 1u)) >> 16;
    return (unsigned short)r;
}
__device__ inline float ldf(const void* p, int i, int f32) {
    return f32 ? ((const float*)p)[i] : bf2f(((const unsigned short*)p)[i]);
}
__device__ inline int lde(const int* ei, int idx, int is64) {
    return is64 ? ei[2 * idx] : ei[idx];
}

// ---- K_det: input dtype layouts (deterministic, every launch) ----
__global__ void k_det(const void* x, const int* ei, int* flags) {
    __shared__ int h1, h2;
    if (threadIdx.x == 0) { h1 = 0; h2 = 0; }
    __syncthreads();
    const unsigned short* xs = (const unsigned short*)x;
    int c1 = 0;
    for (int i = threadIdx.x * 2; i < 65536; i += 512)
        if ((xs[i] & 0x7f80u) == 0x7f80u) c1++;   // fp32 mantissa halves ~1/256; bf16 never
    int c2 = 0;
    for (int i = threadIdx.x * 2 + 1; i < 8192; i += 512)
        if (ei[i] != 0) c2++;                      // int64 high words are 0
    atomicAdd(&h1, c1);
    atomicAdd(&h2, c2);
    __syncthreads();
    if (threadIdx.x == 0) { flags[0] = (h1 >= 8); flags[1] = (h2 < 8); }
}

// ---- K0: zero counts/cursor ----
__global__ void k0_init(int* counts, int* cursor, int N) {
    int i = blockIdx.x * blockDim.x + threadIdx.x;
    if (i <= N) counts[i] = 0;
    if (i < N) cursor[i] = 0;
}

// ---- K_conv: W -> transposed bf16 hi/lo (once, not per GEMM block) ----
__global__ __launch_bounds__(256) void k_conv(
    const void* __restrict__ W, const int* __restrict__ flags,
    unsigned short* __restrict__ WhT, unsigned short* __restrict__ WlT)
{
    int f32 = flags[0];
    int idx = blockIdx.x * 256 + threadIdx.x;   // 64 blocks
    if (idx >= 128 * 128) return;
    int n = idx >> 7, k = idx & 127;
    float v = ldf(W, k * 128 + n, f32);
    unsigned short h = f2bf(v);
    WhT[idx] = h;
    WlT[idx] = f2bf(v - bf2f(h));
}

// ---- K1: proj = x@W via bf16x3 MFMA, vectorized staging + fused scores ----
__global__ __launch_bounds__(256) void k1_gemm(
    const void* __restrict__ x, const unsigned short* __restrict__ WhT,
    const unsigned short* __restrict__ WlT, const void* __restrict__ a_src,
    const void* __restrict__ a_trg, const int* __restrict__ flags,
    unsigned short* __restrict__ projb, float* __restrict__ ssrc,
    float* __restrict__ strg, int N)
{
    __shared__ __align__(16) unsigned short WT[128 * 136];
    int t = threadIdx.x;
    int f32 = flags[0];
    for (int i = t; i < 2048; i += 256) {
        int row = i >> 4, ch = (i & 15) * 8;
        *(short8*)&WT[row * 136 + ch] = *(const short8*)&WhT[row * 128 + ch];
    }
    __syncthreads();
    int wave = t >> 6, lane = t & 63;
    int col = lane & 15, quad = lane >> 4;
    int row0 = blockIdx.x * 64 + wave * 16;
    int m = row0 + col;
    if (m >= N) m = N - 1;
    short8 ah[4], al[4];
    if (f32) {
        const float* xf = (const float*)x + (size_t)m * 128 + quad * 8;
#pragma unroll
        for (int kb = 0; kb < 4; kb++) {
            float4 v0 = *(const float4*)(xf + kb * 32);
            float4 v1 = *(const float4*)(xf + kb * 32 + 4);
            float vv[8] = {v0.x, v0.y, v0.z, v0.w, v1.x, v1.y, v1.z, v1.w};
#pragma unroll
            for (int j = 0; j < 8; j++) {
                unsigned short h = f2bf(vv[j]);
                ah[kb][j] = (short)h;
                al[kb][j] = (short)f2bf(vv[j] - bf2f(h));
            }
        }
    } else {
        const unsigned short* xb = (const unsigned short*)x + (size_t)m * 128 + quad * 8;
#pragma unroll
        for (int kb = 0; kb < 4; kb++)
            ah[kb] = *(const short8*)(xb + kb * 32);
    }
    floatx4 acc[8];
#pragma unroll
    for (int c = 0; c < 8; c++) acc[c] = (floatx4){0.f, 0.f, 0.f, 0.f};
#pragma unroll
    for (int c = 0; c < 8; c++) {
        const short8* bp = (const short8*)(&WT[(c * 16 + col) * 136 + quad * 8]);
        short8 b0 = bp[0], b1 = bp[4], b2 = bp[8], b3 = bp[12];
        acc[c] = __builtin_amdgcn_mfma_f32_16x16x32_bf16(ah[0], b0, acc[c], 0, 0, 0);
        acc[c] = __builtin_amdgcn_mfma_f32_16x16x32_bf16(ah[1], b1, acc[c], 0, 0, 0);
        acc[c] = __builtin_amdgcn_mfma_f32_16x16x32_bf16(ah[2], b2, acc[c], 0, 0, 0);
        acc[c] = __builtin_amdgcn_mfma_f32_16x16x32_bf16(ah[3], b3, acc[c], 0, 0, 0);
        if (f32) {
            acc[c] = __builtin_amdgcn_mfma_f32_16x16x32_bf16(al[0], b0, acc[c], 0, 0, 0);
            acc[c] = __builtin_amdgcn_mfma_f32_16x16x32_bf16(al[1], b1, acc[c], 0, 0, 0);
            acc[c] = __builtin_amdgcn_mfma_f32_16x16x32_bf16(al[2], b2, acc[c], 0, 0, 0);
            acc[c] = __builtin_amdgcn_mfma_f32_16x16x32_bf16(al[3], b3, acc[c], 0, 0, 0);
        }
    }
    if (f32) {
        __syncthreads();
        for (int i = t; i < 2048; i += 256) {
            int row = i >> 4, ch = (i & 15) * 8;
            *(short8*)&WT[row * 136 + ch] = *(const short8*)&WlT[row * 128 + ch];
        }
        __syncthreads();
#pragma unroll
        for (int c = 0; c < 8; c++) {
            const short8* bp = (const short8*)(&WT[(c * 16 + col) * 136 + quad * 8]);
            acc[c] = __builtin_amdgcn_mfma_f32_16x16x32_bf16(ah[0], bp[0], acc[c], 0, 0, 0);
            acc[c] = __builtin_amdgcn_mfma_f32_16x16x32_bf16(ah[1], bp[4], acc[c], 0, 0, 0);
            acc[c] = __builtin_amdgcn_mfma_f32_16x16x32_bf16(ah[2], bp[8], acc[c], 0, 0, 0);
            acc[c] = __builtin_amdgcn_mfma_f32_16x16x32_bf16(ah[3], bp[12], acc[c], 0, 0, 0);
        }
    }
#pragma unroll
    for (int r = 0; r < 4; r++) {
        int row = row0 + quad * 4 + r;
        if (row < N) {
#pragma unroll
            for (int c = 0; c < 8; c++)
                projb[(size_t)row * 128 + c * 16 + col] = f2bf(acc[c][r]);
        }
    }
    float asv[8], atv[8];
#pragma unroll
    for (int c = 0; c < 8; c++) {
        int j = c * 16 + col;
        asv[c] = ldf(a_src, j, f32);
        atv[c] = ldf(a_trg, j, f32);
    }
#pragma unroll
    for (int r = 0; r < 4; r++) {
        int row = row0 + quad * 4 + r;
        float ps[4] = {0.f, 0.f, 0.f, 0.f}, pt[4] = {0.f, 0.f, 0.f, 0.f};
#pragma unroll
        for (int c = 0; c < 8; c++) {
            int h = c >> 1;
            ps[h] += acc[c][r] * asv[c];
            pt[h] += acc[c][r] * atv[c];
        }
#pragma unroll
        for (int k = 1; k < 16; k <<= 1) {
#pragma unroll
            for (int h = 0; h < 4; h++) {
                ps[h] += __shfl_xor(ps[h], k, 16);
                pt[h] += __shfl_xor(pt[h], k, 16);
            }
        }
        if (col == 0 && row < N) {
#pragma unroll
            for (int h = 0; h < 4; h++) {
                ssrc[(size_t)row * 4 + h] = ps[h];
                strg[(size_t)row * 4 + h] = pt[h];
            }
        }
    }
}

__device__ inline void edge_scores(const float* ssrc, const float* strg,
                                   int src, int trg, float* v) {
    float4 a = *(const float4*)(ssrc + (size_t)src * 4);
    float4 b = *(const float4*)(strg + (size_t)trg * 4);
    v[0] = a.x + b.x; v[1] = a.y + b.y; v[2] = a.z + b.z; v[3] = a.w + b.w;
#pragma unroll
    for (int h = 0; h < 4; h++) v[h] = v[h] > 0.f ? v[h] : 0.2f * v[h];
}

// ---- KE: in-degree histogram + per-block max (no same-address atomics) ----
__global__ __launch_bounds__(256) void kE_count_max(
    const int* __restrict__ ei, const float* __restrict__ ssrc,
    const float* __restrict__ strg, const int* __restrict__ flags,
    int* __restrict__ counts, float* __restrict__ blockmax, int E, int N)
{
    int e64 = flags[1];
    int e = blockIdx.x * 256 + threadIdx.x;
    float m = -3.0e38f;
    if (e < E) {
        int src = min(max(lde(ei, e, e64), 0), N - 1);
        int trg = min(max(lde(ei, E + e, e64), 0), N - 1);
        atomicAdd(&counts[trg], 1);
        float v[4];
        edge_scores(ssrc, strg, src, trg, v);
        m = fmaxf(fmaxf(v[0], v[1]), fmaxf(v[2], v[3]));
    }
#pragma unroll
    for (int k = 1; k < 64; k <<= 1) m = fmaxf(m, __shfl_xor(m, k, 64));
    __shared__ float wm[4];
    if ((threadIdx.x & 63) == 0) wm[threadIdx.x >> 6] = m;
    __syncthreads();
    if (threadIdx.x == 0)
        blockmax[blockIdx.x] = fmaxf(fmaxf(wm[0], wm[1]), fmaxf(wm[2], wm[3]));
}

// ---- S1: per-block sums of counts (coalesced) ----
__global__ __launch_bounds__(256) void kS1_psum(
    const int* __restrict__ counts, int* __restrict__ partials, int NP1)
{
    int idx = blockIdx.x * 256 + threadIdx.x;
    int v = (idx < NP1) ? counts[idx] : 0;
#pragma unroll
    for (int k = 1; k < 64; k <<= 1) v += __shfl_xor(v, k, 64);
    __shared__ int wsum[4];
    if ((threadIdx.x & 63) == 0) wsum[threadIdx.x >> 6] = v;
    __syncthreads();
    if (threadIdx.x == 0)
        partials[blockIdx.x] = wsum[0] + wsum[1] + wsum[2] + wsum[3];
}

// ---- S2: exclusive scan of partials (<=256) + Mval reduction (1 block) ----
__global__ __launch_bounds__(256) void kS2_scanp(
    int* __restrict__ partials, int nb,
    const float* __restrict__ blockmax, float* __restrict__ Mval, int nbm)
{
    int t = threadIdx.x;
    if (nb <= 256) {
        __shared__ int lds[256];
        int v = (t < nb) ? partials[t] : 0;
        lds[t] = v;
        __syncthreads();
        int incl = v;
        for (int st = 1; st < 256; st <<= 1) {
            int add = (t >= st) ? lds[t - st] : 0;
            __syncthreads();
            incl += add;
            lds[t] = incl;
            __syncthreads();
        }
        if (t < nb) partials[t] = incl - v;
    } else if (t == 0) {
        int run = 0;
        for (int i = 0; i < nb; i++) { int c = partials[i]; partials[i] = run; run += c; }
    }
    __syncthreads();
    float m = -3.0e38f;
    for (int i = t; i < nbm; i += 256) m = fmaxf(m, blockmax[i]);
#pragma unroll
    for (int k = 1; k < 64; k <<= 1) m = fmaxf(m, __shfl_xor(m, k, 64));
    __shared__ float wm[4];
    if ((t & 63) == 0) wm[t >> 6] = m;
    __syncthreads();
    if (t == 0) *Mval = fmaxf(fmaxf(wm[0], wm[1]), fmaxf(wm[2], wm[3]));
}

// ---- S3: per-block exclusive scan + base -> offsets (coalesced) ----
__global__ __launch_bounds__(256) void kS3_offs(
    const int* __restrict__ counts, const int* __restrict__ partials,
    int* __restrict__ offsets, int NP1)
{
    int t = threadIdx.x;
    int idx = blockIdx.x * 256 + t;
    int v = (idx < NP1) ? counts[idx] : 0;
    __shared__ int lds[256];
    lds[t] = v;
    __syncthreads();
    int incl = v;
    for (int st = 1; st < 256; st <<= 1) {
        int add = (t >= st) ? lds[t - st] : 0;
        __syncthreads();
        incl += add;
        lds[t] = incl;
        __syncthreads();
    }
    if (idx < NP1) offsets[idx] = partials[blockIdx.x] + incl - v;
}

// ---- K2c: CSR scatter of src only (4 B/edge; no eexp scatter) ----
__global__ __launch_bounds__(256) void k2c_scatter(
    const int* __restrict__ ei, const int* __restrict__ offsets,
    const int* __restrict__ flags, int* __restrict__ cursor,
    int* __restrict__ esrc, int E, int N)
{
    int e64 = flags[1];
    int e = blockIdx.x * 256 + threadIdx.x;
    if (e >= E) return;
    int src = min(max(lde(ei, e, e64), 0), N - 1);
    int trg = min(max(lde(ei, E + e, e64), 0), N - 1);
    int pos = offsets[trg] + atomicAdd(&cursor[trg], 1);
    if (pos >= 0 && pos < E) esrc[pos] = src;
}

// ---- K3: single-pass softmax-aggregate (unnormalized acc, final scale) ----
__global__ __launch_bounds__(256) void k3_agg(
    const int* __restrict__ offsets, const int* __restrict__ esrc,
    const float* __restrict__ ssrc, const float* __restrict__ strg,
    const unsigned short* __restrict__ projb, const void* __restrict__ x,
    const void* __restrict__ bias, const int* __restrict__ flags,
    const float* __restrict__ Mval, float* __restrict__ out, int N, int E)
{
    int w = threadIdx.x >> 6;
    int lane = threadIdx.x & 63;
    int n = blockIdx.x * 4 + w;
    int f32 = flags[0];
    bool valid = (n < N);
    int nc = valid ? n : N - 1;
    int off = offsets[nc];
    int d = offsets[nc + 1] - off;
    d = max(0, min(d, E));
    if (!valid) d = 0;
    float M = *Mval;
    float4 stv = *(const float4*)(strg + (size_t)nc * 4);
    float st[4] = {stv.x, stv.y, stv.z, stv.w};

    __shared__ int dmax_s[4];
    if (lane == 0) dmax_s[w] = d;
    __syncthreads();
    int dmx = max(max(dmax_s[0], dmax_s[1]), max(dmax_s[2], dmax_s[3]));

    __shared__ int lsrc[4][64];
    __shared__ float latt[4][64 * 5];
    float den[4] = {0.f, 0.f, 0.f, 0.f};   // per-lane partials from staged edges
    float acc0 = 0.f, acc1 = 0.f;          // unnormalized weighted sums
    int h01 = lane >> 4;                   // head of features 2*lane, 2*lane+1
    for (int base = 0; base < dmx; base += 64) {
        int cd = min(64, d - base);
        if (lane < cd) {
            int s = min(max(esrc[off + base + lane], 0), N - 1);
            lsrc[w][lane] = s;
            float4 ssv = *(const float4*)(ssrc + (size_t)s * 4);
            float sv[4] = {ssv.x, ssv.y, ssv.z, ssv.w};
#pragma unroll
            for (int h = 0; h < 4; h++) {
                float v = sv[h] + st[h];
                v = v > 0.f ? v : 0.2f * v;
                float ev = __expf(v - M);
                latt[w][lane * 5 + h] = ev;
                den[h] += ev;
            }
        }
        __syncthreads();
        for (int k = 0; k < cd; k++) {
            int s = lsrc[w][k];
            float ev = latt[w][k * 5 + h01];
            unsigned p = *(const unsigned*)(projb + (size_t)s * 128 + lane * 2);
            acc0 = fmaf(bf2f((unsigned short)(p & 0xffffu)), ev, acc0);
            acc1 = fmaf(bf2f((unsigned short)(p >> 16)), ev, acc1);
        }
        __syncthreads();
    }
    // reduce denominators across lanes, then scale once
#pragma unroll
    for (int k = 1; k < 64; k <<= 1)
#pragma unroll
        for (int h = 0; h < 4; h++) den[h] += __shfl_xor(den[h], k, 64);
    float inv = 1.0f / (den[h01] + 1e-16f);
    acc0 *= inv;
    acc1 *= inv;

    if (!valid) return;
    int j0 = lane * 2;
    float o0 = acc0 + ldf(x, n * 128 + j0, f32) + ldf(bias, j0, f32);
    float o1 = acc1 + ldf(x, n * 128 + j0 + 1, f32) + ldf(bias, j0 + 1, f32);
    o0 = o0 > 0.f ? o0 : __expf(o0) - 1.f;
    o1 = o1 > 0.f ? o1 : __expf(o1) - 1.f;
    out[(size_t)n * 128 + j0]     = o0;
    out[(size_t)n * 128 + j0 + 1] = o1;
}

extern "C" void kernel_launch(void* const* d_in, const int* in_sizes, int n_in,
                              void* d_out, int out_size, void* d_ws, size_t ws_size,
                              hipStream_t stream)
{
    const void* x     = d_in[0];
    const int*  ei    = (const int*)d_in[1];
    const void* W     = d_in[2];
    const void* a_src = d_in[3];
    const void* a_trg = d_in[4];
    const void* bias  = d_in[5];
    float* out = (float*)d_out;
    int N = in_sizes[0] / 128;
    int E = N * 16;
    if (in_sizes[1] / 2 < E) E = in_sizes[1] / 2;
    int nbE = (E + 255) / 256;
    int NP1 = N + 1;
    int nbS = (NP1 + 255) / 256;

    char* ws = (char*)d_ws;
    size_t o = 0;
    auto alloc = [&](size_t bytes) {
        size_t r = o;
        o = (o + bytes + 255) & ~(size_t)255;
        return r;
    };
    int* flags = (int*)(ws + alloc(256));
    unsigned short* projb = (unsigned short*)(ws + alloc((size_t)N * 128 * 2));
    float* ssrc  = (float*)(ws + alloc((size_t)N * 4 * 4));
    float* strg  = (float*)(ws + alloc((size_t)N * 4 * 4));
    float* Mval  = (float*)(ws + alloc(256));
    int* counts  = (int*)(ws + alloc((size_t)NP1 * 4));
    int* offsets = (int*)(ws + alloc((size_t)NP1 * 4));
    int* cursor  = (int*)(ws + alloc((size_t)N * 4));
    int* esrc    = (int*)(ws + alloc((size_t)E * 4));
    float* blockmax = (float*)(ws + alloc((size_t)nbE * 4));
    int* partials = (int*)(ws + alloc((size_t)nbS * 4));
    unsigned short* WhT = (unsigned short*)(ws + alloc(128 * 128 * 2));
    unsigned short* WlT = (unsigned short*)(ws + alloc(128 * 128 * 2));

    k_det<<<1, 256, 0, stream>>>(x, ei, flags);
    k0_init<<<(N + 256) / 256, 256, 0, stream>>>(counts, cursor, N);
    k_conv<<<64, 256, 0, stream>>>(W, flags, WhT, WlT);
    k1_gemm<<<(N + 63) / 64, 256, 0, stream>>>(x, WhT, WlT, a_src, a_trg, flags,
                                               projb, ssrc, strg, N);
    kE_count_max<<<nbE, 256, 0, stream>>>(ei, ssrc, strg, flags, counts, blockmax, E, N);
    kS1_psum<<<nbS, 256, 0, stream>>>(counts, partials, NP1);
    kS2_scanp<<<1, 256, 0, stream>>>(partials, nbS, blockmax, Mval, nbE);
    kS3_offs<<<nbS, 256, 0, stream>>>(counts, partials, offsets, NP1);
    k2c_scatter<<<nbE, 256, 0, stream>>>(ei, offsets, flags, cursor, esrc, E, N);
    k3_agg<<<(N + 3) / 4, 256, 0, stream>>>(offsets, esrc, ssrc, strg, projb, x, bias,
                                            flags, Mval, out, N, E);
}